// Round 4
// baseline (834.762 us; speedup 1.0000x reference)
//
#include <hip/hip_runtime.h>
#include <math.h>

#define FEAT 2048
#define HD 1024
#define FH 4096
#define NN 8192

using s16x8 = __attribute__((ext_vector_type(8))) short;
using f32x4 = __attribute__((ext_vector_type(4))) float;

#define GLOBAL_AS __attribute__((address_space(1)))
#define LDS_AS __attribute__((address_space(3)))

__device__ __forceinline__ void gload_lds16(const void* g, void* l) {
    __builtin_amdgcn_global_load_lds((const GLOBAL_AS unsigned int*)g,
                                     (LDS_AS unsigned int*)l, 16, 0, 0);
}

__device__ __forceinline__ unsigned short f2bf(float f) {
    union { float f; unsigned u; } v; v.f = f;
    unsigned r = v.u + 0x7FFFu + ((v.u >> 16) & 1u);  // RNE
    return (unsigned short)(r >> 16);
}

__device__ __forceinline__ float fast_sig(float x) { return 1.0f / (1.0f + __expf(-x)); }
__device__ __forceinline__ float fast_tanh(float x) {
    float ax = fabsf(x);
    float e = __expf(2.0f * ax);
    float r = 1.0f - 2.0f / (e + 1.0f);
    return copysignf(r, x);
}

// ---------------------------------------------------------------------------
// fused fp32 -> bf16 convert for feat, Wx, Wh
// ---------------------------------------------------------------------------
__global__ __launch_bounds__(256) void convert_all_kernel(
    const float* __restrict__ feat, const float* __restrict__ Wx,
    const float* __restrict__ Wh, unsigned short* __restrict__ feat_b,
    unsigned short* __restrict__ Wx_b, unsigned short* __restrict__ Wh_b)
{
    const size_t n1 = (size_t)NN * FEAT;
    const size_t n2 = n1 + (size_t)FH * FEAT;
    size_t i = ((size_t)blockIdx.x * 256 + threadIdx.x) * 8;
    const float* s; unsigned short* d;
    if (i < n1)      { s = feat + i;        d = feat_b + i; }
    else if (i < n2) { s = Wx + (i - n1);   d = Wx_b + (i - n1); }
    else             { s = Wh + (i - n2);   d = Wh_b + (i - n2); }
    float4 a = *(const float4*)s;
    float4 b = *(const float4*)(s + 4);
    unsigned short r[8] = {f2bf(a.x), f2bf(a.y), f2bf(a.z), f2bf(a.w),
                           f2bf(b.x), f2bf(b.y), f2bf(b.z), f2bf(b.w)};
    *(s16x8*)d = *(const s16x8*)r;
}

// also zeroes the persistent-kernel barrier counters (bar[0..15])
__global__ __launch_bounds__(256) void init_kernel(
    const float* __restrict__ root_h, const float* __restrict__ root_c,
    unsigned short* __restrict__ h_buf, float* __restrict__ c_buf,
    int* __restrict__ bar)
{
    const int i = blockIdx.x * 256 + threadIdx.x;
    if (i < HD) { h_buf[i] = f2bf(root_h[i]); c_buf[i] = root_c[i]; }
    if (i < 16) bar[i] = 0;
}

// ---------------------------------------------------------------------------
// xproj = feat @ Wx^T + (bx+bh)  (bf16 MFMA, fp32 out). m97 128x128 BK=32.
// NO XCD swizzle: inputs are L3-fit; swizzle measured -11% (R3: FETCH x3.4).
// ---------------------------------------------------------------------------
__global__ __launch_bounds__(256) void xproj_mfma(
    const unsigned short* __restrict__ Ab,
    const unsigned short* __restrict__ Bb,
    const float* __restrict__ bx, const float* __restrict__ bh,
    float* __restrict__ xproj)
{
    __shared__ unsigned short As[128 * 32];
    __shared__ unsigned short Bs[128 * 32];
    const int tid = threadIdx.x;
    const int wid = tid >> 6;
    const int lane = tid & 63;
    const int bm = blockIdx.x * 128;
    const int bn = blockIdx.y * 128;
    const int wm = (wid & 1) * 64;
    const int wn = (wid >> 1) * 64;

    const int srow = wid * 16 + (lane >> 2);
    const int sk = (lane & 3) * 8;
    const unsigned short* gA0 = Ab + (size_t)(bm + srow) * FEAT + sk;
    const unsigned short* gA1 = Ab + (size_t)(bm + 64 + srow) * FEAT + sk;
    const unsigned short* gB0 = Bb + (size_t)(bn + srow) * FEAT + sk;
    const unsigned short* gB1 = Bb + (size_t)(bn + 64 + srow) * FEAT + sk;
    unsigned short* lA0 = As + wid * 512;
    unsigned short* lA1 = As + 2048 + wid * 512;
    unsigned short* lB0 = Bs + wid * 512;
    unsigned short* lB1 = Bs + 2048 + wid * 512;

    f32x4 acc[4][4];
    #pragma unroll
    for (int i = 0; i < 4; ++i)
        #pragma unroll
        for (int j = 0; j < 4; ++j) { f32x4 z = {0.f, 0.f, 0.f, 0.f}; acc[i][j] = z; }

    const int fr = lane & 15;
    const int fk = (lane >> 4) * 8;

    for (int k0 = 0; k0 < FEAT; k0 += 32) {
        gload_lds16(gA0 + k0, lA0);
        gload_lds16(gA1 + k0, lA1);
        gload_lds16(gB0 + k0, lB0);
        gload_lds16(gB1 + k0, lB1);
        __syncthreads();

        s16x8 aF[4], bF[4];
        #pragma unroll
        for (int i = 0; i < 4; ++i)
            aF[i] = *(const s16x8*)&As[(wm + i * 16 + fr) * 32 + fk];
        #pragma unroll
        for (int j = 0; j < 4; ++j)
            bF[j] = *(const s16x8*)&Bs[(wn + j * 16 + fr) * 32 + fk];
        #pragma unroll
        for (int i = 0; i < 4; ++i)
            #pragma unroll
            for (int j = 0; j < 4; ++j)
                acc[i][j] = __builtin_amdgcn_mfma_f32_16x16x32_bf16(aF[i], bF[j], acc[i][j], 0, 0, 0);
        __syncthreads();
    }

    const int fq = lane >> 4;
    #pragma unroll
    for (int j = 0; j < 4; ++j) {
        const int col = bn + wn + j * 16 + fr;
        const float bias = bx[col] + bh[col];
        #pragma unroll
        for (int i = 0; i < 4; ++i) {
            const int rowb = bm + wm + i * 16 + fq * 4;
            #pragma unroll
            for (int reg = 0; reg < 4; ++reg)
                xproj[(size_t)(rowb + reg) * FH + col] = acc[i][j][reg] + bias;
        }
    }
}

// ---------------------------------------------------------------------------
// Shared gate epilogue
// ---------------------------------------------------------------------------
__device__ __forceinline__ void level_epilogue(
    f32x4 (&acc)[4][4], const float* __restrict__ xproj,
    const int* __restrict__ parent, unsigned short* __restrict__ h_buf,
    float* __restrict__ c_buf, float* __restrict__ out,
    int t0, int lim, int wm, int col, int fq)
{
    #pragma unroll
    for (int i = 0; i < 4; ++i) {
        #pragma unroll
        for (int reg = 0; reg < 4; ++reg) {
            const int t = t0 + wm + i * 16 + fq * 4 + reg;
            if (t < lim) {
                const int p = parent[t];
                const size_t xb = (size_t)t * FH + col;
                const float gi = acc[i][0][reg] + xproj[xb];
                const float go = acc[i][1][reg] + xproj[xb + HD];
                const float gf = acc[i][2][reg] + xproj[xb + 2 * HD];
                const float gu = acc[i][3][reg] + xproj[xb + 3 * HD];
                const float cp = c_buf[(size_t)(p + 1) * HD + col];
                const float c = fast_sig(gi) * fast_tanh(gu) + fast_sig(gf) * cp;
                const float h = fast_sig(go) * fast_tanh(c);
                c_buf[(size_t)(t + 1) * HD + col] = c;
                h_buf[(size_t)(t + 1) * HD + col] = f2bf(h);
                out[(size_t)t * HD + col] = h;
            }
        }
    }
}

// ---------------------------------------------------------------------------
// BK=128 tile body (XOR-swizzled both-sides, rule #21). 64 KB LDS.
// ---------------------------------------------------------------------------
__device__ __forceinline__ void bk128_tile(
    unsigned short* As, unsigned short* Bs,
    const unsigned short* const (&gA)[8], const unsigned short* const (&gB)[8],
    f32x4 (&acc)[4][4], int wm, int wn16, int fr, int fkb)
{
    for (int k0 = 0; k0 < HD; k0 += 128) {
        #pragma unroll
        for (int q = 0; q < 8; ++q) {
            gload_lds16(gA[q] + k0, (char*)As + q * 4096 + (threadIdx.x >> 6) * 1024);
            gload_lds16(gB[q] + k0, (char*)Bs + q * 4096 + (threadIdx.x >> 6) * 1024);
        }
        __syncthreads();

        #pragma unroll
        for (int kk = 0; kk < 4; ++kk) {
            s16x8 aF[4], bF[4];
            #pragma unroll
            for (int i = 0; i < 4; ++i) {
                const int r = wm + i * 16 + fr;
                const int byteIn = (kk * 64 + fkb) ^ ((r & 7) << 4);
                aF[i] = *(const s16x8*)((const char*)As + r * 256 + byteIn);
            }
            #pragma unroll
            for (int g = 0; g < 4; ++g) {
                const int r = g * 32 + wn16 + fr;
                const int byteIn = (kk * 64 + fkb) ^ ((r & 7) << 4);
                bF[g] = *(const s16x8*)((const char*)Bs + r * 256 + byteIn);
            }
            #pragma unroll
            for (int i = 0; i < 4; ++i)
                #pragma unroll
                for (int g = 0; g < 4; ++g)
                    acc[i][g] = __builtin_amdgcn_mfma_f32_16x16x32_bf16(aF[i], bF[g], acc[i][g], 0, 0, 0);
        }
        __syncthreads();
    }
}

// ---------------------------------------------------------------------------
// Persistent kernel: levels 0..9 (counts 1..512) in one launch, device-scope
// atomic barrier between levels. Grid = 128 blocks (4 node-rows x 32 col-
// blocks) — co-resident by construction (<= 1 block/CU).
// ---------------------------------------------------------------------------
#define NB_SMALL 128

__device__ __forceinline__ void grid_barrier(int* bar, int lev) {
    __syncthreads();
    __threadfence();   // agent-scope release (cross-XCD L2 writeback)
    if (threadIdx.x == 0) {
        __hip_atomic_fetch_add(&bar[lev], 1, __ATOMIC_RELEASE, __HIP_MEMORY_SCOPE_AGENT);
        while (__hip_atomic_load(&bar[lev], __ATOMIC_ACQUIRE, __HIP_MEMORY_SCOPE_AGENT) < NB_SMALL)
            __builtin_amdgcn_s_sleep(2);
    }
    __syncthreads();
    __threadfence();   // agent-scope acquire (invalidate stale L1/L2)
}

__global__ __launch_bounds__(256) void levels_small_persistent(
    const float* __restrict__ xproj, const unsigned short* __restrict__ Whb,
    const int* __restrict__ parent, unsigned short* __restrict__ h_buf,
    float* __restrict__ c_buf, float* __restrict__ out, int* __restrict__ bar)
{
    __shared__ unsigned short As[128 * 128];
    __shared__ unsigned short Bs[128 * 128];
    const int tid = threadIdx.x;
    const int wid = tid >> 6;
    const int lane = tid & 63;
    const int br = (int)blockIdx.x >> 5;          // 0..3 node-row
    const int jg0 = ((int)blockIdx.x & 31) * 32;  // within-gate col block
    const int wm = (wid & 1) * 64;
    const int wn16 = (wid >> 1) * 16;
    const int fr = lane & 15;
    const int fkb = (lane >> 4) * 16;
    const int srow_b = tid >> 4;
    const int rowbyte = (tid & 15) * 16;

    // B-side pointers: fixed across levels
    const unsigned short* gB[8];
    #pragma unroll
    for (int q = 0; q < 8; ++q) {
        const int r = q * 16 + srow_b;
        const int sk = (rowbyte ^ ((r & 7) << 4)) >> 1;
        const int whrow = ((r >> 5) << 10) + jg0 + (r & 31);
        gB[q] = Whb + (size_t)whrow * HD + sk;
    }

    for (int lev = 0; lev < 10; ++lev) {
        const int start = (1 << lev) - 1;
        const int lim = start + (1 << lev);
        const int t0 = start + br * 128;
        if (t0 < lim) {
            const unsigned short* gA[8];
            #pragma unroll
            for (int q = 0; q < 8; ++q) {
                const int r = q * 16 + srow_b;
                const int sk = (rowbyte ^ ((r & 7) << 4)) >> 1;
                const int tA = min(t0 + r, lim - 1);
                gA[q] = h_buf + (size_t)(parent[tA] + 1) * HD + sk;
            }
            f32x4 acc[4][4];
            #pragma unroll
            for (int i = 0; i < 4; ++i)
                #pragma unroll
                for (int g = 0; g < 4; ++g) { f32x4 z = {0.f, 0.f, 0.f, 0.f}; acc[i][g] = z; }

            bk128_tile(As, Bs, gA, gB, acc, wm, wn16, fr, fkb);
            level_epilogue(acc, xproj, parent, h_buf, c_buf, out,
                           t0, lim, wm, jg0 + wn16 + fr, lane >> 4);
        }
        grid_barrier(bar, lev);
    }
}

// ---------------------------------------------------------------------------
// Standalone BK=128 kernel (used for the 1-node straggler level)
// ---------------------------------------------------------------------------
__global__ __launch_bounds__(256) void level_mfma_bk128(
    const float* __restrict__ xproj, const unsigned short* __restrict__ Whb,
    const int* __restrict__ parent, unsigned short* __restrict__ h_buf,
    float* __restrict__ c_buf, float* __restrict__ out,
    int start, int count)
{
    __shared__ unsigned short As[128 * 128];
    __shared__ unsigned short Bs[128 * 128];
    const int tid = threadIdx.x;
    const int wid = tid >> 6;
    const int lane = tid & 63;
    const int t0 = start + blockIdx.x * 128;
    const int jg0 = blockIdx.y * 32;
    const int lim = start + count;
    const int wm = (wid & 1) * 64;
    const int wn16 = (wid >> 1) * 16;
    const int srow_b = tid >> 4;
    const int rowbyte = (tid & 15) * 16;

    const unsigned short* gA[8];
    const unsigned short* gB[8];
    #pragma unroll
    for (int q = 0; q < 8; ++q) {
        const int r = q * 16 + srow_b;
        const int sk = (rowbyte ^ ((r & 7) << 4)) >> 1;
        const int tA = min(t0 + r, lim - 1);
        gA[q] = h_buf + (size_t)(parent[tA] + 1) * HD + sk;
        const int whrow = ((r >> 5) << 10) + jg0 + (r & 31);
        gB[q] = Whb + (size_t)whrow * HD + sk;
    }

    f32x4 acc[4][4];
    #pragma unroll
    for (int i = 0; i < 4; ++i)
        #pragma unroll
        for (int g = 0; g < 4; ++g) { f32x4 z = {0.f, 0.f, 0.f, 0.f}; acc[i][g] = z; }

    const int fr = lane & 15;
    const int fkb = (lane >> 4) * 16;
    bk128_tile(As, Bs, gA, gB, acc, wm, wn16, fr, fkb);
    level_epilogue(acc, xproj, parent, h_buf, c_buf, out,
                   t0, lim, wm, jg0 + wn16 + fr, lane >> 4);
}

// ---------------------------------------------------------------------------
// Large levels (count >= 1024): BK=32 m97 structure, no swizzle.
// ---------------------------------------------------------------------------
__global__ __launch_bounds__(256) void level_mfma(
    const float* __restrict__ xproj, const unsigned short* __restrict__ Whb,
    const int* __restrict__ parent, unsigned short* __restrict__ h_buf,
    float* __restrict__ c_buf, float* __restrict__ out,
    int start, int count)
{
    __shared__ unsigned short As[128 * 32];
    __shared__ unsigned short Bs[128 * 32];
    const int tid = threadIdx.x;
    const int wid = tid >> 6;
    const int lane = tid & 63;
    const int t0 = start + blockIdx.x * 128;
    const int jg0 = blockIdx.y * 32;
    const int lim = start + count;
    const int wm = (wid & 1) * 64;
    const int wn16 = (wid >> 1) * 16;

    const int srow = wid * 16 + (lane >> 2);
    const int sk = (lane & 3) * 8;
    const int tA0 = min(t0 + srow, lim - 1);
    const int tA1 = min(t0 + 64 + srow, lim - 1);
    const unsigned short* gA0 = h_buf + (size_t)(parent[tA0] + 1) * HD + sk;
    const unsigned short* gA1 = h_buf + (size_t)(parent[tA1] + 1) * HD + sk;
    const int r0 = srow, r1 = 64 + srow;
    const unsigned short* gB0 = Whb + (size_t)((r0 >> 5) * HD + jg0 + (r0 & 31)) * HD + sk;
    const unsigned short* gB1 = Whb + (size_t)((r1 >> 5) * HD + jg0 + (r1 & 31)) * HD + sk;
    unsigned short* lA0 = As + wid * 512;
    unsigned short* lA1 = As + 2048 + wid * 512;
    unsigned short* lB0 = Bs + wid * 512;
    unsigned short* lB1 = Bs + 2048 + wid * 512;

    f32x4 acc[4][4];
    #pragma unroll
    for (int i = 0; i < 4; ++i)
        #pragma unroll
        for (int g = 0; g < 4; ++g) { f32x4 z = {0.f, 0.f, 0.f, 0.f}; acc[i][g] = z; }

    const int fr = lane & 15;
    const int fk = (lane >> 4) * 8;

    for (int k0 = 0; k0 < HD; k0 += 32) {
        gload_lds16(gA0 + k0, lA0);
        gload_lds16(gA1 + k0, lA1);
        gload_lds16(gB0 + k0, lB0);
        gload_lds16(gB1 + k0, lB1);
        __syncthreads();

        s16x8 aF[4], bF[4];
        #pragma unroll
        for (int i = 0; i < 4; ++i)
            aF[i] = *(const s16x8*)&As[(wm + i * 16 + fr) * 32 + fk];
        #pragma unroll
        for (int g = 0; g < 4; ++g)
            bF[g] = *(const s16x8*)&Bs[(g * 32 + wn16 + fr) * 32 + fk];
        #pragma unroll
        for (int i = 0; i < 4; ++i)
            #pragma unroll
            for (int g = 0; g < 4; ++g)
                acc[i][g] = __builtin_amdgcn_mfma_f32_16x16x32_bf16(aF[i], bF[g], acc[i][g], 0, 0, 0);
        __syncthreads();
    }

    level_epilogue(acc, xproj, parent, h_buf, c_buf, out,
                   t0, lim, wm, jg0 + wn16 + fr, lane >> 4);
}

extern "C" void kernel_launch(void* const* d_in, const int* in_sizes, int n_in,
                              void* d_out, int out_size, void* d_ws, size_t ws_size,
                              hipStream_t stream) {
    const float* feat   = (const float*)d_in[0];
    const float* Wx     = (const float*)d_in[1];
    const float* bx     = (const float*)d_in[2];
    const float* Wh     = (const float*)d_in[3];
    const float* bh     = (const float*)d_in[4];
    const int*   parent = (const int*)d_in[5];
    const float* root_c = (const float*)d_in[6];
    const float* root_h = (const float*)d_in[7];
    float* out = (float*)d_out;

    char* ws = (char*)d_ws;
    float* xproj = (float*)ws;                          ws += (size_t)NN * FH * 4;
    float* c_buf = (float*)ws;                          ws += (size_t)(NN + 1) * HD * 4;
    unsigned short* feat_b = (unsigned short*)ws;       ws += (size_t)NN * FEAT * 2;
    unsigned short* Wx_b = (unsigned short*)ws;         ws += (size_t)FH * FEAT * 2;
    unsigned short* Wh_b = (unsigned short*)ws;         ws += (size_t)FH * HD * 2;
    unsigned short* h_buf = (unsigned short*)ws;        ws += (size_t)(NN + 1) * HD * 2;
    int* bar = (int*)ws;                                ws += 64;

    const size_t ntot = (size_t)NN * FEAT + (size_t)FH * FEAT + (size_t)FH * HD;
    convert_all_kernel<<<(unsigned)(ntot / 8 / 256), 256, 0, stream>>>(
        feat, Wx, Wh, feat_b, Wx_b, Wh_b);
    init_kernel<<<4, 256, 0, stream>>>(root_h, root_c, h_buf, c_buf, bar);

    dim3 g1(NN / 128, FH / 128);
    xproj_mfma<<<g1, 256, 0, stream>>>(feat_b, Wx_b, bx, bh, xproj);

    // levels 0..9 (counts 1..512) fused into one persistent launch
    levels_small_persistent<<<NB_SMALL, 256, 0, stream>>>(
        xproj, Wh_b, parent, h_buf, c_buf, out, bar);

    // large levels
    for (int start = 1023, sz = 1024; start < NN - 1; start += sz, sz *= 2) {
        const int count = (sz < NN - 1 - start) ? sz : (NN - 1 - start);
        dim3 g2((count + 127) / 128, HD / 32);
        level_mfma<<<g2, 256, 0, stream>>>(xproj, Wh_b, parent, h_buf, c_buf,
                                           out, start, count);
    }
    // straggler node 8191
    dim3 g3(1, HD / 32);
    level_mfma_bk128<<<g3, 256, 0, stream>>>(xproj, Wh_b, parent, h_buf, c_buf,
                                             out, 8191, 1);
}

// Round 5
// 531.179 us; speedup vs baseline: 1.5715x; 1.5715x over previous
//
#include <hip/hip_runtime.h>
#include <math.h>

#define FEAT 2048
#define HD 1024
#define FH 4096
#define NN 8192

using s16x8 = __attribute__((ext_vector_type(8))) short;
using f32x4 = __attribute__((ext_vector_type(4))) float;

#define GLOBAL_AS __attribute__((address_space(1)))
#define LDS_AS __attribute__((address_space(3)))

__device__ __forceinline__ void gload_lds16(const void* g, void* l) {
    __builtin_amdgcn_global_load_lds((const GLOBAL_AS unsigned int*)g,
                                     (LDS_AS unsigned int*)l, 16, 0, 0);
}

__device__ __forceinline__ unsigned short f2bf(float f) {
    union { float f; unsigned u; } v; v.f = f;
    unsigned r = v.u + 0x7FFFu + ((v.u >> 16) & 1u);  // RNE
    return (unsigned short)(r >> 16);
}

__device__ __forceinline__ float fast_sig(float x) { return 1.0f / (1.0f + __expf(-x)); }
__device__ __forceinline__ float fast_tanh(float x) {
    float ax = fabsf(x);
    float e = __expf(2.0f * ax);
    float r = 1.0f - 2.0f / (e + 1.0f);
    return copysignf(r, x);
}

// ---------------------------------------------------------------------------
// fused fp32 -> bf16 convert for feat, Wx, Wh
// ---------------------------------------------------------------------------
__global__ __launch_bounds__(256) void convert_all_kernel(
    const float* __restrict__ feat, const float* __restrict__ Wx,
    const float* __restrict__ Wh, unsigned short* __restrict__ feat_b,
    unsigned short* __restrict__ Wx_b, unsigned short* __restrict__ Wh_b)
{
    const size_t n1 = (size_t)NN * FEAT;
    const size_t n2 = n1 + (size_t)FH * FEAT;
    size_t i = ((size_t)blockIdx.x * 256 + threadIdx.x) * 8;
    const float* s; unsigned short* d;
    if (i < n1)      { s = feat + i;        d = feat_b + i; }
    else if (i < n2) { s = Wx + (i - n1);   d = Wx_b + (i - n1); }
    else             { s = Wh + (i - n2);   d = Wh_b + (i - n2); }
    float4 a = *(const float4*)s;
    float4 b = *(const float4*)(s + 4);
    unsigned short r[8] = {f2bf(a.x), f2bf(a.y), f2bf(a.z), f2bf(a.w),
                           f2bf(b.x), f2bf(b.y), f2bf(b.z), f2bf(b.w)};
    *(s16x8*)d = *(const s16x8*)r;
}

__global__ __launch_bounds__(256) void init_kernel(
    const float* __restrict__ root_h, const float* __restrict__ root_c,
    unsigned short* __restrict__ h_buf, float* __restrict__ c_buf)
{
    const int i = blockIdx.x * 256 + threadIdx.x;
    if (i < HD) { h_buf[i] = f2bf(root_h[i]); c_buf[i] = root_c[i]; }
}

// ---------------------------------------------------------------------------
// xproj = feat @ Wx^T + (bx+bh)  (bf16 MFMA, fp32 out). m97 128x128 BK=32.
// NO XCD swizzle (R3: swizzle => FETCH x3.4, -11%; inputs are L3-fit).
// ---------------------------------------------------------------------------
__global__ __launch_bounds__(256) void xproj_mfma(
    const unsigned short* __restrict__ Ab,
    const unsigned short* __restrict__ Bb,
    const float* __restrict__ bx, const float* __restrict__ bh,
    float* __restrict__ xproj)
{
    __shared__ unsigned short As[128 * 32];
    __shared__ unsigned short Bs[128 * 32];
    const int tid = threadIdx.x;
    const int wid = tid >> 6;
    const int lane = tid & 63;
    const int bm = blockIdx.x * 128;
    const int bn = blockIdx.y * 128;
    const int wm = (wid & 1) * 64;
    const int wn = (wid >> 1) * 64;

    const int srow = wid * 16 + (lane >> 2);
    const int sk = (lane & 3) * 8;
    const unsigned short* gA0 = Ab + (size_t)(bm + srow) * FEAT + sk;
    const unsigned short* gA1 = Ab + (size_t)(bm + 64 + srow) * FEAT + sk;
    const unsigned short* gB0 = Bb + (size_t)(bn + srow) * FEAT + sk;
    const unsigned short* gB1 = Bb + (size_t)(bn + 64 + srow) * FEAT + sk;
    unsigned short* lA0 = As + wid * 512;
    unsigned short* lA1 = As + 2048 + wid * 512;
    unsigned short* lB0 = Bs + wid * 512;
    unsigned short* lB1 = Bs + 2048 + wid * 512;

    f32x4 acc[4][4];
    #pragma unroll
    for (int i = 0; i < 4; ++i)
        #pragma unroll
        for (int j = 0; j < 4; ++j) { f32x4 z = {0.f, 0.f, 0.f, 0.f}; acc[i][j] = z; }

    const int fr = lane & 15;
    const int fk = (lane >> 4) * 8;

    for (int k0 = 0; k0 < FEAT; k0 += 32) {
        gload_lds16(gA0 + k0, lA0);
        gload_lds16(gA1 + k0, lA1);
        gload_lds16(gB0 + k0, lB0);
        gload_lds16(gB1 + k0, lB1);
        __syncthreads();

        s16x8 aF[4], bF[4];
        #pragma unroll
        for (int i = 0; i < 4; ++i)
            aF[i] = *(const s16x8*)&As[(wm + i * 16 + fr) * 32 + fk];
        #pragma unroll
        for (int j = 0; j < 4; ++j)
            bF[j] = *(const s16x8*)&Bs[(wn + j * 16 + fr) * 32 + fk];
        #pragma unroll
        for (int i = 0; i < 4; ++i)
            #pragma unroll
            for (int j = 0; j < 4; ++j)
                acc[i][j] = __builtin_amdgcn_mfma_f32_16x16x32_bf16(aF[i], bF[j], acc[i][j], 0, 0, 0);
        __syncthreads();
    }

    const int fq = lane >> 4;
    #pragma unroll
    for (int j = 0; j < 4; ++j) {
        const int col = bn + wn + j * 16 + fr;
        const float bias = bx[col] + bh[col];
        #pragma unroll
        for (int i = 0; i < 4; ++i) {
            const int rowb = bm + wm + i * 16 + fq * 4;
            #pragma unroll
            for (int reg = 0; reg < 4; ++reg)
                xproj[(size_t)(rowb + reg) * FH + col] = acc[i][j][reg] + bias;
        }
    }
}

// ---------------------------------------------------------------------------
// Shared gate epilogue
// ---------------------------------------------------------------------------
__device__ __forceinline__ void level_epilogue(
    f32x4 (&acc)[4][4], const float* __restrict__ xproj,
    const int* __restrict__ parent, unsigned short* __restrict__ h_buf,
    float* __restrict__ c_buf, float* __restrict__ out,
    int t0, int lim, int wm, int col, int fq)
{
    #pragma unroll
    for (int i = 0; i < 4; ++i) {
        #pragma unroll
        for (int reg = 0; reg < 4; ++reg) {
            const int t = t0 + wm + i * 16 + fq * 4 + reg;
            if (t < lim) {
                const int p = parent[t];
                const size_t xb = (size_t)t * FH + col;
                const float gi = acc[i][0][reg] + xproj[xb];
                const float go = acc[i][1][reg] + xproj[xb + HD];
                const float gf = acc[i][2][reg] + xproj[xb + 2 * HD];
                const float gu = acc[i][3][reg] + xproj[xb + 3 * HD];
                const float cp = c_buf[(size_t)(p + 1) * HD + col];
                const float c = fast_sig(gi) * fast_tanh(gu) + fast_sig(gf) * cp;
                const float h = fast_sig(go) * fast_tanh(c);
                c_buf[(size_t)(t + 1) * HD + col] = c;
                h_buf[(size_t)(t + 1) * HD + col] = f2bf(h);
                out[(size_t)t * HD + col] = h;
            }
        }
    }
}

// ---------------------------------------------------------------------------
// BK=128 helpers: staged issue + swizzled compute (rule #21: pre-swizzled
// global source + same XOR on ds_read; LDS dest stays linear).
// ---------------------------------------------------------------------------
__device__ __forceinline__ void bk128_issue(
    const unsigned short* const (&gA)[8], const unsigned short* const (&gB)[8],
    int k0, unsigned short* As, unsigned short* Bs, int wbase)
{
    #pragma unroll
    for (int q = 0; q < 8; ++q) {
        gload_lds16(gA[q] + k0, (char*)As + q * 4096 + wbase);
        gload_lds16(gB[q] + k0, (char*)Bs + q * 4096 + wbase);
    }
}

__device__ __forceinline__ void bk128_compute(
    const unsigned short* As, const unsigned short* Bs,
    f32x4 (&acc)[4][4], int wm, int wn16, int fr, int fkb)
{
    #pragma unroll
    for (int kk = 0; kk < 4; ++kk) {
        s16x8 aF[4], bF[4];
        #pragma unroll
        for (int i = 0; i < 4; ++i) {
            const int r = wm + i * 16 + fr;
            const int byteIn = (kk * 64 + fkb) ^ ((r & 7) << 4);
            aF[i] = *(const s16x8*)((const char*)As + r * 256 + byteIn);
        }
        #pragma unroll
        for (int g = 0; g < 4; ++g) {
            const int r = g * 32 + wn16 + fr;
            const int byteIn = (kk * 64 + fkb) ^ ((r & 7) << 4);
            bF[g] = *(const s16x8*)((const char*)Bs + r * 256 + byteIn);
        }
        #pragma unroll
        for (int i = 0; i < 4; ++i)
            #pragma unroll
            for (int g = 0; g < 4; ++g)
                acc[i][g] = __builtin_amdgcn_mfma_f32_16x16x32_bf16(aF[i], bF[g], acc[i][g], 0, 0, 0);
    }
}

// ---------------------------------------------------------------------------
// Small levels (count <= 512): BK=128, DOUBLE-BUFFERED (T3+T4): counted
// vmcnt(16) + raw s_barrier — prefetch tile t+1 while computing tile t.
// Correctness of counted wait: tile t's 16 loads are always the oldest
// outstanding vmem ops, so draining to <=16 remaining completes them.
// ---------------------------------------------------------------------------
__global__ __launch_bounds__(256) void level_bk128_dbuf(
    const float* __restrict__ xproj, const unsigned short* __restrict__ Whb,
    const int* __restrict__ parent, unsigned short* __restrict__ h_buf,
    float* __restrict__ c_buf, float* __restrict__ out,
    int start, int count)
{
    __shared__ unsigned short As0[128 * 128];   // 32 KB each, 128 KB total
    __shared__ unsigned short Bs0[128 * 128];
    __shared__ unsigned short As1[128 * 128];
    __shared__ unsigned short Bs1[128 * 128];
    const int tid = threadIdx.x;
    const int wid = tid >> 6;
    const int lane = tid & 63;
    const int t0 = start + blockIdx.x * 128;
    const int jg0 = blockIdx.y * 32;
    const int lim = start + count;
    const int wm = (wid & 1) * 64;
    const int wn16 = (wid >> 1) * 16;
    const int wbase = wid * 1024;
    const int srow_b = tid >> 4;
    const int rowbyte = (tid & 15) * 16;

    const unsigned short* gA[8];
    const unsigned short* gB[8];
    #pragma unroll
    for (int q = 0; q < 8; ++q) {
        const int r = q * 16 + srow_b;
        const int sk = (rowbyte ^ ((r & 7) << 4)) >> 1;
        const int tA = min(t0 + r, lim - 1);
        gA[q] = h_buf + (size_t)(parent[tA] + 1) * HD + sk;
        const int whrow = ((r >> 5) << 10) + jg0 + (r & 31);
        gB[q] = Whb + (size_t)whrow * HD + sk;
    }

    f32x4 acc[4][4];
    #pragma unroll
    for (int i = 0; i < 4; ++i)
        #pragma unroll
        for (int g = 0; g < 4; ++g) { f32x4 z = {0.f, 0.f, 0.f, 0.f}; acc[i][g] = z; }

    const int fr = lane & 15;
    const int fkb = (lane >> 4) * 16;

    bk128_issue(gA, gB, 0, As0, Bs0, wbase);
    #pragma unroll
    for (int t = 0; t < 8; ++t) {
        unsigned short* curA = (t & 1) ? As1 : As0;
        unsigned short* curB = (t & 1) ? Bs1 : Bs0;
        unsigned short* nxtA = (t & 1) ? As0 : As1;
        unsigned short* nxtB = (t & 1) ? Bs0 : Bs1;
        if (t < 7) {
            bk128_issue(gA, gB, (t + 1) * 128, nxtA, nxtB, wbase);
            asm volatile("s_waitcnt vmcnt(16)" ::: "memory");
        } else {
            asm volatile("s_waitcnt vmcnt(0)" ::: "memory");
        }
        __builtin_amdgcn_s_barrier();
        __builtin_amdgcn_sched_barrier(0);
        bk128_compute(curA, curB, acc, wm, wn16, fr, fkb);
        __builtin_amdgcn_sched_barrier(0);
        __builtin_amdgcn_s_barrier();
    }

    level_epilogue(acc, xproj, parent, h_buf, c_buf, out,
                   t0, lim, wm, jg0 + wn16 + fr, lane >> 4);
}

// ---------------------------------------------------------------------------
// Large levels (count >= 1024): BK=32 m97 structure (throughput regime,
// implicit multi-block overlap per CU).
// ---------------------------------------------------------------------------
__global__ __launch_bounds__(256) void level_mfma(
    const float* __restrict__ xproj, const unsigned short* __restrict__ Whb,
    const int* __restrict__ parent, unsigned short* __restrict__ h_buf,
    float* __restrict__ c_buf, float* __restrict__ out,
    int start, int count)
{
    __shared__ unsigned short As[128 * 32];
    __shared__ unsigned short Bs[128 * 32];
    const int tid = threadIdx.x;
    const int wid = tid >> 6;
    const int lane = tid & 63;
    const int t0 = start + blockIdx.x * 128;
    const int jg0 = blockIdx.y * 32;
    const int lim = start + count;
    const int wm = (wid & 1) * 64;
    const int wn16 = (wid >> 1) * 16;

    const int srow = wid * 16 + (lane >> 2);
    const int sk = (lane & 3) * 8;
    const int tA0 = min(t0 + srow, lim - 1);
    const int tA1 = min(t0 + 64 + srow, lim - 1);
    const unsigned short* gA0 = h_buf + (size_t)(parent[tA0] + 1) * HD + sk;
    const unsigned short* gA1 = h_buf + (size_t)(parent[tA1] + 1) * HD + sk;
    const int r0 = srow, r1 = 64 + srow;
    const unsigned short* gB0 = Whb + (size_t)((r0 >> 5) * HD + jg0 + (r0 & 31)) * HD + sk;
    const unsigned short* gB1 = Whb + (size_t)((r1 >> 5) * HD + jg0 + (r1 & 31)) * HD + sk;
    unsigned short* lA0 = As + wid * 512;
    unsigned short* lA1 = As + 2048 + wid * 512;
    unsigned short* lB0 = Bs + wid * 512;
    unsigned short* lB1 = Bs + 2048 + wid * 512;

    f32x4 acc[4][4];
    #pragma unroll
    for (int i = 0; i < 4; ++i)
        #pragma unroll
        for (int g = 0; g < 4; ++g) { f32x4 z = {0.f, 0.f, 0.f, 0.f}; acc[i][g] = z; }

    const int fr = lane & 15;
    const int fk = (lane >> 4) * 8;

    for (int k0 = 0; k0 < HD; k0 += 32) {
        gload_lds16(gA0 + k0, lA0);
        gload_lds16(gA1 + k0, lA1);
        gload_lds16(gB0 + k0, lB0);
        gload_lds16(gB1 + k0, lB1);
        __syncthreads();

        s16x8 aF[4], bF[4];
        #pragma unroll
        for (int i = 0; i < 4; ++i)
            aF[i] = *(const s16x8*)&As[(wm + i * 16 + fr) * 32 + fk];
        #pragma unroll
        for (int g = 0; g < 4; ++g)
            bF[g] = *(const s16x8*)&Bs[(g * 32 + wn16 + fr) * 32 + fk];
        #pragma unroll
        for (int i = 0; i < 4; ++i)
            #pragma unroll
            for (int g = 0; g < 4; ++g)
                acc[i][g] = __builtin_amdgcn_mfma_f32_16x16x32_bf16(aF[i], bF[g], acc[i][g], 0, 0, 0);
        __syncthreads();
    }

    level_epilogue(acc, xproj, parent, h_buf, c_buf, out,
                   t0, lim, wm, jg0 + wn16 + fr, lane >> 4);
}

extern "C" void kernel_launch(void* const* d_in, const int* in_sizes, int n_in,
                              void* d_out, int out_size, void* d_ws, size_t ws_size,
                              hipStream_t stream) {
    const float* feat   = (const float*)d_in[0];
    const float* Wx     = (const float*)d_in[1];
    const float* bx     = (const float*)d_in[2];
    const float* Wh     = (const float*)d_in[3];
    const float* bh     = (const float*)d_in[4];
    const int*   parent = (const int*)d_in[5];
    const float* root_c = (const float*)d_in[6];
    const float* root_h = (const float*)d_in[7];
    float* out = (float*)d_out;

    char* ws = (char*)d_ws;
    float* xproj = (float*)ws;                          ws += (size_t)NN * FH * 4;
    float* c_buf = (float*)ws;                          ws += (size_t)(NN + 1) * HD * 4;
    unsigned short* feat_b = (unsigned short*)ws;       ws += (size_t)NN * FEAT * 2;
    unsigned short* Wx_b = (unsigned short*)ws;         ws += (size_t)FH * FEAT * 2;
    unsigned short* Wh_b = (unsigned short*)ws;         ws += (size_t)FH * HD * 2;
    unsigned short* h_buf = (unsigned short*)ws;        ws += (size_t)(NN + 1) * HD * 2;

    const size_t ntot = (size_t)NN * FEAT + (size_t)FH * FEAT + (size_t)FH * HD;
    convert_all_kernel<<<(unsigned)(ntot / 8 / 256), 256, 0, stream>>>(
        feat, Wx, Wh, feat_b, Wx_b, Wh_b);
    init_kernel<<<4, 256, 0, stream>>>(root_h, root_c, h_buf, c_buf);

    dim3 g1(NN / 128, FH / 128);
    xproj_mfma<<<g1, 256, 0, stream>>>(feat_b, Wx_b, bx, bh, xproj);

    for (int start = 0, sz = 1; start < NN; start += sz, sz *= 2) {
        const int count = (sz < NN - start) ? sz : (NN - start);
        dim3 g2((count + 127) / 128, HD / 32);
        if (count >= 1024)
            level_mfma<<<g2, 256, 0, stream>>>(xproj, Wh_b, parent, h_buf, c_buf,
                                               out, start, count);
        else
            level_bk128_dbuf<<<g2, 256, 0, stream>>>(xproj, Wh_b, parent, h_buf,
                                                     c_buf, out, start, count);
    }
}

// Round 6
// 511.294 us; speedup vs baseline: 1.6326x; 1.0389x over previous
//
#include <hip/hip_runtime.h>
#include <math.h>

#define FEAT 2048
#define HD 1024
#define FH 4096
#define NN 8192

using s16x8 = __attribute__((ext_vector_type(8))) short;
using f32x4 = __attribute__((ext_vector_type(4))) float;

#define GLOBAL_AS __attribute__((address_space(1)))
#define LDS_AS __attribute__((address_space(3)))

__device__ __forceinline__ void gload_lds16(const void* g, void* l) {
    __builtin_amdgcn_global_load_lds((const GLOBAL_AS unsigned int*)g,
                                     (LDS_AS unsigned int*)l, 16, 0, 0);
}

__device__ __forceinline__ unsigned short f2bf(float f) {
    union { float f; unsigned u; } v; v.f = f;
    unsigned r = v.u + 0x7FFFu + ((v.u >> 16) & 1u);  // RNE
    return (unsigned short)(r >> 16);
}

__device__ __forceinline__ float fast_sig(float x) { return 1.0f / (1.0f + __expf(-x)); }
__device__ __forceinline__ float fast_tanh(float x) {
    float ax = fabsf(x);
    float e = __expf(2.0f * ax);
    float r = 1.0f - 2.0f / (e + 1.0f);
    return copysignf(r, x);
}

// ---------------------------------------------------------------------------
// fused fp32 -> bf16 convert for feat, Wx, Wh
// ---------------------------------------------------------------------------
__global__ __launch_bounds__(256) void convert_all_kernel(
    const float* __restrict__ feat, const float* __restrict__ Wx,
    const float* __restrict__ Wh, unsigned short* __restrict__ feat_b,
    unsigned short* __restrict__ Wx_b, unsigned short* __restrict__ Wh_b)
{
    const size_t n1 = (size_t)NN * FEAT;
    const size_t n2 = n1 + (size_t)FH * FEAT;
    size_t i = ((size_t)blockIdx.x * 256 + threadIdx.x) * 8;
    const float* s; unsigned short* d;
    if (i < n1)      { s = feat + i;        d = feat_b + i; }
    else if (i < n2) { s = Wx + (i - n1);   d = Wx_b + (i - n1); }
    else             { s = Wh + (i - n2);   d = Wh_b + (i - n2); }
    float4 a = *(const float4*)s;
    float4 b = *(const float4*)(s + 4);
    unsigned short r[8] = {f2bf(a.x), f2bf(a.y), f2bf(a.z), f2bf(a.w),
                           f2bf(b.x), f2bf(b.y), f2bf(b.z), f2bf(b.w)};
    *(s16x8*)d = *(const s16x8*)r;
}

__global__ __launch_bounds__(256) void init_kernel(
    const float* __restrict__ root_h, const float* __restrict__ root_c,
    unsigned short* __restrict__ h_buf, float* __restrict__ c_buf)
{
    const int i = blockIdx.x * 256 + threadIdx.x;
    if (i < HD) { h_buf[i] = f2bf(root_h[i]); c_buf[i] = root_c[i]; }
}

// ---------------------------------------------------------------------------
// xproj = feat @ Wx^T + (bx+bh), 256x256 tile, BK=64, 8 waves, 8-phase-style
// schedule (T2 swizzle + T3/T4 counted-drain dbuf + T5 setprio).
// LDS 128 KiB: buf d at d*64KB { A 32KB | B 32KB }, rows of 128B (64 bf16),
// XOR-swizzle byte ^= (row&7)<<4 on global source AND ds_read (rule #21).
// ---------------------------------------------------------------------------
__global__ __launch_bounds__(512, 2) void xproj_8ph(
    const unsigned short* __restrict__ Ab,   // feat_b [8192][2048]
    const unsigned short* __restrict__ Bb,   // Wx_b   [4096][2048]
    const float* __restrict__ bx, const float* __restrict__ bh,
    float* __restrict__ xproj)
{
    __shared__ char lds[131072];
    const int tid = threadIdx.x;
    const int wid = tid >> 6;          // 0..7
    const int lane = tid & 63;
    const int wr = wid >> 2;           // 0..1  (M half)
    const int wc = wid & 3;            // 0..3  (N quarter)
    const int bm = blockIdx.x * 256;
    const int bn = blockIdx.y * 256;
    const int fr = lane & 15;
    const int fq = lane >> 4;          // 0..3

    // staging: thread stages row q*64 + (tid>>3), slot (tid&7)^(row&7)
    const int srow = tid >> 3;                     // 0..63
    const int sslot = (tid & 7) ^ (srow & 7);
    const unsigned short* gA[4];
    const unsigned short* gB[4];
    #pragma unroll
    for (int q = 0; q < 4; ++q) {
        gA[q] = Ab + (size_t)(bm + q * 64 + srow) * FEAT + sslot * 8;
        gB[q] = Bb + (size_t)(bn + q * 64 + srow) * FEAT + sslot * 8;
    }
    const int ldsoff = tid * 16;   // linear dest within each 8KB q-chunk

    f32x4 acc[8][4];
    #pragma unroll
    for (int i = 0; i < 8; ++i)
        #pragma unroll
        for (int j = 0; j < 4; ++j) { f32x4 z = {0.f, 0.f, 0.f, 0.f}; acc[i][j] = z; }

    // prologue: stage tile 0 into buf 0
    #pragma unroll
    for (int q = 0; q < 4; ++q) {
        gload_lds16(gA[q], lds + q * 8192 + ldsoff);
        gload_lds16(gB[q], lds + 32768 + q * 8192 + ldsoff);
    }
    asm volatile("s_waitcnt vmcnt(0)" ::: "memory");
    __builtin_amdgcn_s_barrier();

    for (int t = 0; t < 32; ++t) {
        const int d = t & 1;
        const char* LA = lds + d * 65536;
        const char* LB = LA + 32768;
        char* SA = lds + (d ^ 1) * 65536;
        char* SB = SA + 32768;
        const int knext = (t + 1) * 64;

        #pragma unroll
        for (int p = 0; p < 4; ++p) {
            const int mh = p >> 1, nh = p & 1;   // C-quadrant
            // ds-reads for this quadrant (12 x ds_read_b128, conflict-free)
            s16x8 aF[4][2], bF[2][2];
            #pragma unroll
            for (int i = 0; i < 4; ++i) {
                const int row = wr * 128 + (mh * 4 + i) * 16 + fr;
                #pragma unroll
                for (int kk = 0; kk < 2; ++kk) {
                    const int kbyte = kk * 64 + fq * 16;
                    aF[i][kk] = *(const s16x8*)(LA + row * 128 + (kbyte ^ ((row & 7) << 4)));
                }
            }
            #pragma unroll
            for (int j = 0; j < 2; ++j) {
                const int row = wc * 64 + (nh * 2 + j) * 16 + fr;
                #pragma unroll
                for (int kk = 0; kk < 2; ++kk) {
                    const int kbyte = kk * 64 + fq * 16;
                    bF[j][kk] = *(const s16x8*)(LB + row * 128 + (kbyte ^ ((row & 7) << 4)));
                }
            }
            // stage next tile early (phases 0,1 -> drain has 2 phases of cover)
            if (t < 31 && p < 2) {
                gload_lds16(gA[2 * p] + knext,     SA + (2 * p) * 8192 + ldsoff);
                gload_lds16(gB[2 * p] + knext,     SB + (2 * p) * 8192 + ldsoff);
                gload_lds16(gA[2 * p + 1] + knext, SA + (2 * p + 1) * 8192 + ldsoff);
                gload_lds16(gB[2 * p + 1] + knext, SB + (2 * p + 1) * 8192 + ldsoff);
            }
            __builtin_amdgcn_s_barrier();
            __builtin_amdgcn_s_setprio(1);
            #pragma unroll
            for (int i = 0; i < 4; ++i)
                #pragma unroll
                for (int j = 0; j < 2; ++j)
                    #pragma unroll
                    for (int kk = 0; kk < 2; ++kk)
                        acc[mh * 4 + i][nh * 2 + j] = __builtin_amdgcn_mfma_f32_16x16x32_bf16(
                            aF[i][kk], bF[j][kk], acc[mh * 4 + i][nh * 2 + j], 0, 0, 0);
            __builtin_amdgcn_s_setprio(0);
            if (p < 3) {
                __builtin_amdgcn_s_barrier();
            } else {
                // tile boundary: staged loads for t+1 must be LDS-visible
                asm volatile("s_waitcnt vmcnt(0)" ::: "memory");
                __builtin_amdgcn_s_barrier();
            }
        }
    }

    // epilogue: D row = fq*4+reg, col = fr (m89 layout)
    #pragma unroll
    for (int j = 0; j < 4; ++j) {
        const int col = bn + wc * 64 + j * 16 + fr;
        const float bias = bx[col] + bh[col];
        #pragma unroll
        for (int i = 0; i < 8; ++i) {
            const int rowb = bm + wr * 128 + i * 16 + fq * 4;
            #pragma unroll
            for (int reg = 0; reg < 4; ++reg)
                xproj[(size_t)(rowb + reg) * FH + col] = acc[i][j][reg] + bias;
        }
    }
}

// ---------------------------------------------------------------------------
// Shared gate epilogue
// ---------------------------------------------------------------------------
__device__ __forceinline__ void level_epilogue(
    f32x4 (&acc)[4][4], const float* __restrict__ xproj,
    const int* __restrict__ parent, unsigned short* __restrict__ h_buf,
    float* __restrict__ c_buf, float* __restrict__ out,
    int t0, int lim, int wm, int col, int fq)
{
    #pragma unroll
    for (int i = 0; i < 4; ++i) {
        #pragma unroll
        for (int reg = 0; reg < 4; ++reg) {
            const int t = t0 + wm + i * 16 + fq * 4 + reg;
            if (t < lim) {
                const int p = parent[t];
                const size_t xb = (size_t)t * FH + col;
                const float gi = acc[i][0][reg] + xproj[xb];
                const float go = acc[i][1][reg] + xproj[xb + HD];
                const float gf = acc[i][2][reg] + xproj[xb + 2 * HD];
                const float gu = acc[i][3][reg] + xproj[xb + 3 * HD];
                const float cp = c_buf[(size_t)(p + 1) * HD + col];
                const float c = fast_sig(gi) * fast_tanh(gu) + fast_sig(gf) * cp;
                const float h = fast_sig(go) * fast_tanh(c);
                c_buf[(size_t)(t + 1) * HD + col] = c;
                h_buf[(size_t)(t + 1) * HD + col] = f2bf(h);
                out[(size_t)t * HD + col] = h;
            }
        }
    }
}

// ---------------------------------------------------------------------------
// BK=128 helpers (small levels)
// ---------------------------------------------------------------------------
__device__ __forceinline__ void bk128_issue(
    const unsigned short* const (&gA)[8], const unsigned short* const (&gB)[8],
    int k0, unsigned short* As, unsigned short* Bs, int wbase)
{
    #pragma unroll
    for (int q = 0; q < 8; ++q) {
        gload_lds16(gA[q] + k0, (char*)As + q * 4096 + wbase);
        gload_lds16(gB[q] + k0, (char*)Bs + q * 4096 + wbase);
    }
}

__device__ __forceinline__ void bk128_compute(
    const unsigned short* As, const unsigned short* Bs,
    f32x4 (&acc)[4][4], int wm, int wn16, int fr, int fkb)
{
    #pragma unroll
    for (int kk = 0; kk < 4; ++kk) {
        s16x8 aF[4], bF[4];
        #pragma unroll
        for (int i = 0; i < 4; ++i) {
            const int r = wm + i * 16 + fr;
            const int byteIn = (kk * 64 + fkb) ^ ((r & 7) << 4);
            aF[i] = *(const s16x8*)((const char*)As + r * 256 + byteIn);
        }
        #pragma unroll
        for (int g = 0; g < 4; ++g) {
            const int r = g * 32 + wn16 + fr;
            const int byteIn = (kk * 64 + fkb) ^ ((r & 7) << 4);
            bF[g] = *(const s16x8*)((const char*)Bs + r * 256 + byteIn);
        }
        #pragma unroll
        for (int i = 0; i < 4; ++i)
            #pragma unroll
            for (int g = 0; g < 4; ++g)
                acc[i][g] = __builtin_amdgcn_mfma_f32_16x16x32_bf16(aF[i], bF[g], acc[i][g], 0, 0, 0);
    }
}

// ---------------------------------------------------------------------------
// Small levels (count <= 512): BK=128 double-buffered (R5-proven)
// ---------------------------------------------------------------------------
__global__ __launch_bounds__(256) void level_bk128_dbuf(
    const float* __restrict__ xproj, const unsigned short* __restrict__ Whb,
    const int* __restrict__ parent, unsigned short* __restrict__ h_buf,
    float* __restrict__ c_buf, float* __restrict__ out,
    int start, int count)
{
    __shared__ unsigned short As0[128 * 128];
    __shared__ unsigned short Bs0[128 * 128];
    __shared__ unsigned short As1[128 * 128];
    __shared__ unsigned short Bs1[128 * 128];
    const int tid = threadIdx.x;
    const int wid = tid >> 6;
    const int lane = tid & 63;
    const int t0 = start + blockIdx.x * 128;
    const int jg0 = blockIdx.y * 32;
    const int lim = start + count;
    const int wm = (wid & 1) * 64;
    const int wn16 = (wid >> 1) * 16;
    const int wbase = wid * 1024;
    const int srow_b = tid >> 4;
    const int rowbyte = (tid & 15) * 16;

    const unsigned short* gA[8];
    const unsigned short* gB[8];
    #pragma unroll
    for (int q = 0; q < 8; ++q) {
        const int r = q * 16 + srow_b;
        const int sk = (rowbyte ^ ((r & 7) << 4)) >> 1;
        const int tA = min(t0 + r, lim - 1);
        gA[q] = h_buf + (size_t)(parent[tA] + 1) * HD + sk;
        const int whrow = ((r >> 5) << 10) + jg0 + (r & 31);
        gB[q] = Whb + (size_t)whrow * HD + sk;
    }

    f32x4 acc[4][4];
    #pragma unroll
    for (int i = 0; i < 4; ++i)
        #pragma unroll
        for (int g = 0; g < 4; ++g) { f32x4 z = {0.f, 0.f, 0.f, 0.f}; acc[i][g] = z; }

    const int fr = lane & 15;
    const int fkb = (lane >> 4) * 16;

    bk128_issue(gA, gB, 0, As0, Bs0, wbase);
    #pragma unroll
    for (int t = 0; t < 8; ++t) {
        unsigned short* curA = (t & 1) ? As1 : As0;
        unsigned short* curB = (t & 1) ? Bs1 : Bs0;
        unsigned short* nxtA = (t & 1) ? As0 : As1;
        unsigned short* nxtB = (t & 1) ? Bs0 : Bs1;
        if (t < 7) {
            bk128_issue(gA, gB, (t + 1) * 128, nxtA, nxtB, wbase);
            asm volatile("s_waitcnt vmcnt(16)" ::: "memory");
        } else {
            asm volatile("s_waitcnt vmcnt(0)" ::: "memory");
        }
        __builtin_amdgcn_s_barrier();
        __builtin_amdgcn_sched_barrier(0);
        bk128_compute(curA, curB, acc, wm, wn16, fr, fkb);
        __builtin_amdgcn_sched_barrier(0);
        __builtin_amdgcn_s_barrier();
    }

    level_epilogue(acc, xproj, parent, h_buf, c_buf, out,
                   t0, lim, wm, jg0 + wn16 + fr, lane >> 4);
}

// ---------------------------------------------------------------------------
// Large levels (count >= 1024): BK=32 m97 structure
// ---------------------------------------------------------------------------
__global__ __launch_bounds__(256) void level_mfma(
    const float* __restrict__ xproj, const unsigned short* __restrict__ Whb,
    const int* __restrict__ parent, unsigned short* __restrict__ h_buf,
    float* __restrict__ c_buf, float* __restrict__ out,
    int start, int count)
{
    __shared__ unsigned short As[128 * 32];
    __shared__ unsigned short Bs[128 * 32];
    const int tid = threadIdx.x;
    const int wid = tid >> 6;
    const int lane = tid & 63;
    const int t0 = start + blockIdx.x * 128;
    const int jg0 = blockIdx.y * 32;
    const int lim = start + count;
    const int wm = (wid & 1) * 64;
    const int wn16 = (wid >> 1) * 16;

    const int srow = wid * 16 + (lane >> 2);
    const int sk = (lane & 3) * 8;
    const int tA0 = min(t0 + srow, lim - 1);
    const int tA1 = min(t0 + 64 + srow, lim - 1);
    const unsigned short* gA0 = h_buf + (size_t)(parent[tA0] + 1) * HD + sk;
    const unsigned short* gA1 = h_buf + (size_t)(parent[tA1] + 1) * HD + sk;
    const int r0 = srow, r1 = 64 + srow;
    const unsigned short* gB0 = Whb + (size_t)((r0 >> 5) * HD + jg0 + (r0 & 31)) * HD + sk;
    const unsigned short* gB1 = Whb + (size_t)((r1 >> 5) * HD + jg0 + (r1 & 31)) * HD + sk;
    unsigned short* lA0 = As + wid * 512;
    unsigned short* lA1 = As + 2048 + wid * 512;
    unsigned short* lB0 = Bs + wid * 512;
    unsigned short* lB1 = Bs + 2048 + wid * 512;

    f32x4 acc[4][4];
    #pragma unroll
    for (int i = 0; i < 4; ++i)
        #pragma unroll
        for (int g = 0; g < 4; ++g) { f32x4 z = {0.f, 0.f, 0.f, 0.f}; acc[i][g] = z; }

    const int fr = lane & 15;
    const int fk = (lane >> 4) * 8;

    for (int k0 = 0; k0 < HD; k0 += 32) {
        gload_lds16(gA0 + k0, lA0);
        gload_lds16(gA1 + k0, lA1);
        gload_lds16(gB0 + k0, lB0);
        gload_lds16(gB1 + k0, lB1);
        __syncthreads();

        s16x8 aF[4], bF[4];
        #pragma unroll
        for (int i = 0; i < 4; ++i)
            aF[i] = *(const s16x8*)&As[(wm + i * 16 + fr) * 32 + fk];
        #pragma unroll
        for (int g = 0; g < 4; ++g)
            bF[g] = *(const s16x8*)&Bs[(g * 32 + wn16 + fr) * 32 + fk];
        #pragma unroll
        for (int i = 0; i < 4; ++i)
            #pragma unroll
            for (int g = 0; g < 4; ++g)
                acc[i][g] = __builtin_amdgcn_mfma_f32_16x16x32_bf16(aF[i], bF[g], acc[i][g], 0, 0, 0);
        __syncthreads();
    }

    level_epilogue(acc, xproj, parent, h_buf, c_buf, out,
                   t0, lim, wm, jg0 + wn16 + fr, lane >> 4);
}

extern "C" void kernel_launch(void* const* d_in, const int* in_sizes, int n_in,
                              void* d_out, int out_size, void* d_ws, size_t ws_size,
                              hipStream_t stream) {
    const float* feat   = (const float*)d_in[0];
    const float* Wx     = (const float*)d_in[1];
    const float* bx     = (const float*)d_in[2];
    const float* Wh     = (const float*)d_in[3];
    const float* bh     = (const float*)d_in[4];
    const int*   parent = (const int*)d_in[5];
    const float* root_c = (const float*)d_in[6];
    const float* root_h = (const float*)d_in[7];
    float* out = (float*)d_out;

    char* ws = (char*)d_ws;
    float* xproj = (float*)ws;                          ws += (size_t)NN * FH * 4;
    float* c_buf = (float*)ws;                          ws += (size_t)(NN + 1) * HD * 4;
    unsigned short* feat_b = (unsigned short*)ws;       ws += (size_t)NN * FEAT * 2;
    unsigned short* Wx_b = (unsigned short*)ws;         ws += (size_t)FH * FEAT * 2;
    unsigned short* Wh_b = (unsigned short*)ws;         ws += (size_t)FH * HD * 2;
    unsigned short* h_buf = (unsigned short*)ws;        ws += (size_t)(NN + 1) * HD * 2;

    const size_t ntot = (size_t)NN * FEAT + (size_t)FH * FEAT + (size_t)FH * HD;
    convert_all_kernel<<<(unsigned)(ntot / 8 / 256), 256, 0, stream>>>(
        feat, Wx, Wh, feat_b, Wx_b, Wh_b);
    init_kernel<<<4, 256, 0, stream>>>(root_h, root_c, h_buf, c_buf);

    dim3 g1(NN / 256, FH / 256);
    xproj_8ph<<<g1, 512, 0, stream>>>(feat_b, Wx_b, bx, bh, xproj);

    for (int start = 0, sz = 1; start < NN; start += sz, sz *= 2) {
        const int count = (sz < NN - start) ? sz : (NN - start);
        dim3 g2((count + 127) / 128, HD / 32);
        if (count >= 1024)
            level_mfma<<<g2, 256, 0, stream>>>(xproj, Wh_b, parent, h_buf, c_buf,
                                               out, start, count);
        else
            level_bk128_dbuf<<<g2, 256, 0, stream>>>(xproj, Wh_b, parent, h_buf,
                                                     c_buf, out, start, count);
    }
}

// Round 7
// 492.263 us; speedup vs baseline: 1.6958x; 1.0387x over previous
//
#include <hip/hip_runtime.h>
#include <math.h>

#define FEAT 2048
#define HD 1024
#define FH 4096
#define NN 8192

using s16x8 = __attribute__((ext_vector_type(8))) short;
using f32x4 = __attribute__((ext_vector_type(4))) float;

#define GLOBAL_AS __attribute__((address_space(1)))
#define LDS_AS __attribute__((address_space(3)))

__device__ __forceinline__ void gload_lds16(const void* g, void* l) {
    __builtin_amdgcn_global_load_lds((const GLOBAL_AS unsigned int*)g,
                                     (LDS_AS unsigned int*)l, 16, 0, 0);
}

__device__ __forceinline__ unsigned short f2bf(float f) {
    union { float f; unsigned u; } v; v.f = f;
    unsigned r = v.u + 0x7FFFu + ((v.u >> 16) & 1u);  // RNE
    return (unsigned short)(r >> 16);
}

__device__ __forceinline__ float fast_sig(float x) { return 1.0f / (1.0f + __expf(-x)); }
__device__ __forceinline__ float fast_tanh(float x) {
    float ax = fabsf(x);
    float e = __expf(2.0f * ax);
    float r = 1.0f - 2.0f / (e + 1.0f);
    return copysignf(r, x);
}

// ---------------------------------------------------------------------------
// fused fp32 -> bf16 convert for feat, Wx, Wh
// ---------------------------------------------------------------------------
__global__ __launch_bounds__(256) void convert_all_kernel(
    const float* __restrict__ feat, const float* __restrict__ Wx,
    const float* __restrict__ Wh, unsigned short* __restrict__ feat_b,
    unsigned short* __restrict__ Wx_b, unsigned short* __restrict__ Wh_b)
{
    const size_t n1 = (size_t)NN * FEAT;
    const size_t n2 = n1 + (size_t)FH * FEAT;
    size_t i = ((size_t)blockIdx.x * 256 + threadIdx.x) * 8;
    const float* s; unsigned short* d;
    if (i < n1)      { s = feat + i;        d = feat_b + i; }
    else if (i < n2) { s = Wx + (i - n1);   d = Wx_b + (i - n1); }
    else             { s = Wh + (i - n2);   d = Wh_b + (i - n2); }
    float4 a = *(const float4*)s;
    float4 b = *(const float4*)(s + 4);
    unsigned short r[8] = {f2bf(a.x), f2bf(a.y), f2bf(a.z), f2bf(a.w),
                           f2bf(b.x), f2bf(b.y), f2bf(b.z), f2bf(b.w)};
    *(s16x8*)d = *(const s16x8*)r;
}

__global__ __launch_bounds__(256) void init_kernel(
    const float* __restrict__ root_h, const float* __restrict__ root_c,
    unsigned short* __restrict__ h_buf, float* __restrict__ c_buf)
{
    const int i = blockIdx.x * 256 + threadIdx.x;
    if (i < HD) { h_buf[i] = f2bf(root_h[i]); c_buf[i] = root_c[i]; }
}

// ---------------------------------------------------------------------------
// xproj = feat @ Wx^T + (bx+bh), 256x256 tile, BK=64, 8 waves.
// kk-split phases: each fragment ds_read'd exactly ONCE per K-tile
// (24 reads + 64 MFMA per tile per wave; R6's quadrant form was 48 reads ->
// LDS-BW-bound at 40% ceiling). 1 barrier + 1 vmcnt(0) drain per tile.
// XOR swizzle byte ^= (row&7)<<4 both-sides (rule #21), 0 bank conflicts (R6).
// ---------------------------------------------------------------------------
__global__ __launch_bounds__(512, 2) void xproj_8ph(
    const unsigned short* __restrict__ Ab,   // feat_b [8192][2048]
    const unsigned short* __restrict__ Bb,   // Wx_b   [4096][2048]
    const float* __restrict__ bx, const float* __restrict__ bh,
    float* __restrict__ xproj)
{
    __shared__ char lds[131072];
    const int tid = threadIdx.x;
    const int wid = tid >> 6;          // 0..7
    const int lane = tid & 63;
    const int wr = wid >> 2;           // 0..1  (M half, 128 rows)
    const int wc = wid & 3;            // 0..3  (N quarter, 64 cols)
    const int bm = blockIdx.x * 256;
    const int bn = blockIdx.y * 256;
    const int fr = lane & 15;
    const int fq = lane >> 4;          // 0..3

    // staging: thread stages row q*64 + (tid>>3), 16B slot (tid&7)^(row&7)
    const int srow = tid >> 3;                     // 0..63
    const int sslot = (tid & 7) ^ (srow & 7);
    const unsigned short* gA[4];
    const unsigned short* gB[4];
    #pragma unroll
    for (int q = 0; q < 4; ++q) {
        gA[q] = Ab + (size_t)(bm + q * 64 + srow) * FEAT + sslot * 8;
        gB[q] = Bb + (size_t)(bn + q * 64 + srow) * FEAT + sslot * 8;
    }
    const int ldsoff = tid * 16;   // linear dest within each 8KB q-chunk

    f32x4 acc[8][4];
    #pragma unroll
    for (int i = 0; i < 8; ++i)
        #pragma unroll
        for (int j = 0; j < 4; ++j) { f32x4 z = {0.f, 0.f, 0.f, 0.f}; acc[i][j] = z; }

    // prologue: stage tile 0 into buf 0
    #pragma unroll
    for (int q = 0; q < 4; ++q) {
        gload_lds16(gA[q], lds + q * 8192 + ldsoff);
        gload_lds16(gB[q], lds + 32768 + q * 8192 + ldsoff);
    }

    for (int t = 0; t < 32; ++t) {
        const int d = t & 1;
        const char* LA = lds + d * 65536;
        const char* LB = LA + 32768;
        char* SA = lds + (d ^ 1) * 65536;
        char* SB = SA + 32768;
        const int knext = (t + 1) * 64;

        // tile t's loads complete; all waves done reading buf d^1
        asm volatile("s_waitcnt vmcnt(0)" ::: "memory");
        __builtin_amdgcn_s_barrier();

        #pragma unroll
        for (int kk = 0; kk < 2; ++kk) {
            const int kbyte = kk * 64 + fq * 16;
            s16x8 aF[8], bF[4];
            #pragma unroll
            for (int i = 0; i < 8; ++i) {
                const int row = wr * 128 + i * 16 + fr;
                aF[i] = *(const s16x8*)(LA + row * 128 + (kbyte ^ ((row & 7) << 4)));
            }
            #pragma unroll
            for (int j = 0; j < 4; ++j) {
                const int row = wc * 64 + j * 16 + fr;
                bF[j] = *(const s16x8*)(LB + row * 128 + (kbyte ^ ((row & 7) << 4)));
            }
            // stage half of next tile (kk0: A, kk1: B) into the other buffer
            if (t < 31) {
                if (kk == 0) {
                    #pragma unroll
                    for (int q = 0; q < 4; ++q)
                        gload_lds16(gA[q] + knext, SA + q * 8192 + ldsoff);
                } else {
                    #pragma unroll
                    for (int q = 0; q < 4; ++q)
                        gload_lds16(gB[q] + knext, SB + q * 8192 + ldsoff);
                }
            }
            __builtin_amdgcn_s_setprio(1);
            #pragma unroll
            for (int i = 0; i < 8; ++i)
                #pragma unroll
                for (int j = 0; j < 4; ++j)
                    acc[i][j] = __builtin_amdgcn_mfma_f32_16x16x32_bf16(
                        aF[i], bF[j], acc[i][j], 0, 0, 0);
            __builtin_amdgcn_s_setprio(0);
        }
    }

    // epilogue: D row = fq*4+reg, col = fr (m89 layout)
    #pragma unroll
    for (int j = 0; j < 4; ++j) {
        const int col = bn + wc * 64 + j * 16 + fr;
        const float bias = bx[col] + bh[col];
        #pragma unroll
        for (int i = 0; i < 8; ++i) {
            const int rowb = bm + wr * 128 + i * 16 + fq * 4;
            #pragma unroll
            for (int reg = 0; reg < 4; ++reg)
                xproj[(size_t)(rowb + reg) * FH + col] = acc[i][j][reg] + bias;
        }
    }
}

// ---------------------------------------------------------------------------
// Shared gate epilogue
// ---------------------------------------------------------------------------
__device__ __forceinline__ void level_epilogue(
    f32x4 (&acc)[4][4], const float* __restrict__ xproj,
    const int* __restrict__ parent, unsigned short* __restrict__ h_buf,
    float* __restrict__ c_buf, float* __restrict__ out,
    int t0, int lim, int wm, int col, int fq)
{
    #pragma unroll
    for (int i = 0; i < 4; ++i) {
        #pragma unroll
        for (int reg = 0; reg < 4; ++reg) {
            const int t = t0 + wm + i * 16 + fq * 4 + reg;
            if (t < lim) {
                const int p = parent[t];
                const size_t xb = (size_t)t * FH + col;
                const float gi = acc[i][0][reg] + xproj[xb];
                const float go = acc[i][1][reg] + xproj[xb + HD];
                const float gf = acc[i][2][reg] + xproj[xb + 2 * HD];
                const float gu = acc[i][3][reg] + xproj[xb + 3 * HD];
                const float cp = c_buf[(size_t)(p + 1) * HD + col];
                const float c = fast_sig(gi) * fast_tanh(gu) + fast_sig(gf) * cp;
                const float h = fast_sig(go) * fast_tanh(c);
                c_buf[(size_t)(t + 1) * HD + col] = c;
                h_buf[(size_t)(t + 1) * HD + col] = f2bf(h);
                out[(size_t)t * HD + col] = h;
            }
        }
    }
}

// ---------------------------------------------------------------------------
// BK=128 helpers (small levels)
// ---------------------------------------------------------------------------
__device__ __forceinline__ void bk128_issue(
    const unsigned short* const (&gA)[8], const unsigned short* const (&gB)[8],
    int k0, unsigned short* As, unsigned short* Bs, int wbase)
{
    #pragma unroll
    for (int q = 0; q < 8; ++q) {
        gload_lds16(gA[q] + k0, (char*)As + q * 4096 + wbase);
        gload_lds16(gB[q] + k0, (char*)Bs + q * 4096 + wbase);
    }
}

__device__ __forceinline__ void bk128_compute(
    const unsigned short* As, const unsigned short* Bs,
    f32x4 (&acc)[4][4], int wm, int wn16, int fr, int fkb)
{
    #pragma unroll
    for (int kk = 0; kk < 4; ++kk) {
        s16x8 aF[4], bF[4];
        #pragma unroll
        for (int i = 0; i < 4; ++i) {
            const int r = wm + i * 16 + fr;
            const int byteIn = (kk * 64 + fkb) ^ ((r & 7) << 4);
            aF[i] = *(const s16x8*)((const char*)As + r * 256 + byteIn);
        }
        #pragma unroll
        for (int g = 0; g < 4; ++g) {
            const int r = g * 32 + wn16 + fr;
            const int byteIn = (kk * 64 + fkb) ^ ((r & 7) << 4);
            bF[g] = *(const s16x8*)((const char*)Bs + r * 256 + byteIn);
        }
        #pragma unroll
        for (int i = 0; i < 4; ++i)
            #pragma unroll
            for (int g = 0; g < 4; ++g)
                acc[i][g] = __builtin_amdgcn_mfma_f32_16x16x32_bf16(aF[i], bF[g], acc[i][g], 0, 0, 0);
    }
}

// ---------------------------------------------------------------------------
// Small levels (count <= 512): BK=128 double-buffered (R5-proven)
// ---------------------------------------------------------------------------
__global__ __launch_bounds__(256) void level_bk128_dbuf(
    const float* __restrict__ xproj, const unsigned short* __restrict__ Whb,
    const int* __restrict__ parent, unsigned short* __restrict__ h_buf,
    float* __restrict__ c_buf, float* __restrict__ out,
    int start, int count)
{
    __shared__ unsigned short As0[128 * 128];
    __shared__ unsigned short Bs0[128 * 128];
    __shared__ unsigned short As1[128 * 128];
    __shared__ unsigned short Bs1[128 * 128];
    const int tid = threadIdx.x;
    const int wid = tid >> 6;
    const int lane = tid & 63;
    const int t0 = start + blockIdx.x * 128;
    const int jg0 = blockIdx.y * 32;
    const int lim = start + count;
    const int wm = (wid & 1) * 64;
    const int wn16 = (wid >> 1) * 16;
    const int wbase = wid * 1024;
    const int srow_b = tid >> 4;
    const int rowbyte = (tid & 15) * 16;

    const unsigned short* gA[8];
    const unsigned short* gB[8];
    #pragma unroll
    for (int q = 0; q < 8; ++q) {
        const int r = q * 16 + srow_b;
        const int sk = (rowbyte ^ ((r & 7) << 4)) >> 1;
        const int tA = min(t0 + r, lim - 1);
        gA[q] = h_buf + (size_t)(parent[tA] + 1) * HD + sk;
        const int whrow = ((r >> 5) << 10) + jg0 + (r & 31);
        gB[q] = Whb + (size_t)whrow * HD + sk;
    }

    f32x4 acc[4][4];
    #pragma unroll
    for (int i = 0; i < 4; ++i)
        #pragma unroll
        for (int g = 0; g < 4; ++g) { f32x4 z = {0.f, 0.f, 0.f, 0.f}; acc[i][g] = z; }

    const int fr = lane & 15;
    const int fkb = (lane >> 4) * 16;

    bk128_issue(gA, gB, 0, As0, Bs0, wbase);
    #pragma unroll
    for (int t = 0; t < 8; ++t) {
        unsigned short* curA = (t & 1) ? As1 : As0;
        unsigned short* curB = (t & 1) ? Bs1 : Bs0;
        unsigned short* nxtA = (t & 1) ? As0 : As1;
        unsigned short* nxtB = (t & 1) ? Bs0 : Bs1;
        if (t < 7) {
            bk128_issue(gA, gB, (t + 1) * 128, nxtA, nxtB, wbase);
            asm volatile("s_waitcnt vmcnt(16)" ::: "memory");
        } else {
            asm volatile("s_waitcnt vmcnt(0)" ::: "memory");
        }
        __builtin_amdgcn_s_barrier();
        __builtin_amdgcn_sched_barrier(0);
        bk128_compute(curA, curB, acc, wm, wn16, fr, fkb);
        __builtin_amdgcn_sched_barrier(0);
        __builtin_amdgcn_s_barrier();
    }

    level_epilogue(acc, xproj, parent, h_buf, c_buf, out,
                   t0, lim, wm, jg0 + wn16 + fr, lane >> 4);
}

// ---------------------------------------------------------------------------
// Large levels (count >= 1024): BK=32 m97 structure
// ---------------------------------------------------------------------------
__global__ __launch_bounds__(256) void level_mfma(
    const float* __restrict__ xproj, const unsigned short* __restrict__ Whb,
    const int* __restrict__ parent, unsigned short* __restrict__ h_buf,
    float* __restrict__ c_buf, float* __restrict__ out,
    int start, int count)
{
    __shared__ unsigned short As[128 * 32];
    __shared__ unsigned short Bs[128 * 32];
    const int tid = threadIdx.x;
    const int wid = tid >> 6;
    const int lane = tid & 63;
    const int t0 = start + blockIdx.x * 128;
    const int jg0 = blockIdx.y * 32;
    const int lim = start + count;
    const int wm = (wid & 1) * 64;
    const int wn16 = (wid >> 1) * 16;

    const int srow = wid * 16 + (lane >> 2);
    const int sk = (lane & 3) * 8;
    const int tA0 = min(t0 + srow, lim - 1);
    const int tA1 = min(t0 + 64 + srow, lim - 1);
    const unsigned short* gA0 = h_buf + (size_t)(parent[tA0] + 1) * HD + sk;
    const unsigned short* gA1 = h_buf + (size_t)(parent[tA1] + 1) * HD + sk;
    const int r0 = srow, r1 = 64 + srow;
    const unsigned short* gB0 = Whb + (size_t)((r0 >> 5) * HD + jg0 + (r0 & 31)) * HD + sk;
    const unsigned short* gB1 = Whb + (size_t)((r1 >> 5) * HD + jg0 + (r1 & 31)) * HD + sk;
    unsigned short* lA0 = As + wid * 512;
    unsigned short* lA1 = As + 2048 + wid * 512;
    unsigned short* lB0 = Bs + wid * 512;
    unsigned short* lB1 = Bs + 2048 + wid * 512;

    f32x4 acc[4][4];
    #pragma unroll
    for (int i = 0; i < 4; ++i)
        #pragma unroll
        for (int g = 0; g < 4; ++g) { f32x4 z = {0.f, 0.f, 0.f, 0.f}; acc[i][g] = z; }

    const int fr = lane & 15;
    const int fk = (lane >> 4) * 8;

    for (int k0 = 0; k0 < HD; k0 += 32) {
        gload_lds16(gA0 + k0, lA0);
        gload_lds16(gA1 + k0, lA1);
        gload_lds16(gB0 + k0, lB0);
        gload_lds16(gB1 + k0, lB1);
        __syncthreads();

        s16x8 aF[4], bF[4];
        #pragma unroll
        for (int i = 0; i < 4; ++i)
            aF[i] = *(const s16x8*)&As[(wm + i * 16 + fr) * 32 + fk];
        #pragma unroll
        for (int g = 0; g < 4; ++g)
            bF[g] = *(const s16x8*)&Bs[(g * 32 + wn16 + fr) * 32 + fk];
        #pragma unroll
        for (int i = 0; i < 4; ++i)
            #pragma unroll
            for (int g = 0; g < 4; ++g)
                acc[i][g] = __builtin_amdgcn_mfma_f32_16x16x32_bf16(aF[i], bF[g], acc[i][g], 0, 0, 0);
        __syncthreads();
    }

    level_epilogue(acc, xproj, parent, h_buf, c_buf, out,
                   t0, lim, wm, jg0 + wn16 + fr, lane >> 4);
}

extern "C" void kernel_launch(void* const* d_in, const int* in_sizes, int n_in,
                              void* d_out, int out_size, void* d_ws, size_t ws_size,
                              hipStream_t stream) {
    const float* feat   = (const float*)d_in[0];
    const float* Wx     = (const float*)d_in[1];
    const float* bx     = (const float*)d_in[2];
    const float* Wh     = (const float*)d_in[3];
    const float* bh     = (const float*)d_in[4];
    const int*   parent = (const int*)d_in[5];
    const float* root_c = (const float*)d_in[6];
    const float* root_h = (const float*)d_in[7];
    float* out = (float*)d_out;

    char* ws = (char*)d_ws;
    float* xproj = (float*)ws;                          ws += (size_t)NN * FH * 4;
    float* c_buf = (float*)ws;                          ws += (size_t)(NN + 1) * HD * 4;
    unsigned short* feat_b = (unsigned short*)ws;       ws += (size_t)NN * FEAT * 2;
    unsigned short* Wx_b = (unsigned short*)ws;         ws += (size_t)FH * FEAT * 2;
    unsigned short* Wh_b = (unsigned short*)ws;         ws += (size_t)FH * HD * 2;
    unsigned short* h_buf = (unsigned short*)ws;        ws += (size_t)(NN + 1) * HD * 2;

    const size_t ntot = (size_t)NN * FEAT + (size_t)FH * FEAT + (size_t)FH * HD;
    convert_all_kernel<<<(unsigned)(ntot / 8 / 256), 256, 0, stream>>>(
        feat, Wx, Wh, feat_b, Wx_b, Wh_b);
    init_kernel<<<4, 256, 0, stream>>>(root_h, root_c, h_buf, c_buf);

    dim3 g1(NN / 256, FH / 256);
    xproj_8ph<<<g1, 512, 0, stream>>>(feat_b, Wx_b, bx, bh, xproj);

    for (int start = 0, sz = 1; start < NN; start += sz, sz *= 2) {
        const int count = (sz < NN - start) ? sz : (NN - start);
        dim3 g2((count + 127) / 128, HD / 32);
        if (count >= 1024)
            level_mfma<<<g2, 256, 0, stream>>>(xproj, Wh_b, parent, h_buf, c_buf,
                                               out, start, count);
        else
            level_bk128_dbuf<<<g2, 256, 0, stream>>>(xproj, Wh_b, parent, h_buf,
                                                     c_buf, out, start, count);
    }
}

// Round 9
// 462.994 us; speedup vs baseline: 1.8030x; 1.0632x over previous
//
#include <hip/hip_runtime.h>
#include <math.h>

#define FEAT 2048
#define HD 1024
#define FH 4096
#define NN 8192

using s16x8 = __attribute__((ext_vector_type(8))) short;
using f32x4 = __attribute__((ext_vector_type(4))) float;

#define GLOBAL_AS __attribute__((address_space(1)))
#define LDS_AS __attribute__((address_space(3)))

__device__ __forceinline__ void gload_lds16(const void* g, void* l) {
    __builtin_amdgcn_global_load_lds((const GLOBAL_AS unsigned int*)g,
                                     (LDS_AS unsigned int*)l, 16, 0, 0);
}

__device__ __forceinline__ unsigned short f2bf(float f) {
    union { float f; unsigned u; } v; v.f = f;
    unsigned r = v.u + 0x7FFFu + ((v.u >> 16) & 1u);  // RNE
    return (unsigned short)(r >> 16);
}

__device__ __forceinline__ float fast_sig(float x) { return 1.0f / (1.0f + __expf(-x)); }
__device__ __forceinline__ float fast_tanh(float x) {
    float ax = fabsf(x);
    float e = __expf(2.0f * ax);
    float r = 1.0f - 2.0f / (e + 1.0f);
    return copysignf(r, x);
}

// ---------------------------------------------------------------------------
// fused fp32 -> bf16 convert for feat, Wx, Wh
// ---------------------------------------------------------------------------
__global__ __launch_bounds__(256) void convert_all_kernel(
    const float* __restrict__ feat, const float* __restrict__ Wx,
    const float* __restrict__ Wh, unsigned short* __restrict__ feat_b,
    unsigned short* __restrict__ Wx_b, unsigned short* __restrict__ Wh_b)
{
    const size_t n1 = (size_t)NN * FEAT;
    const size_t n2 = n1 + (size_t)FH * FEAT;
    size_t i = ((size_t)blockIdx.x * 256 + threadIdx.x) * 8;
    const float* s; unsigned short* d;
    if (i < n1)      { s = feat + i;        d = feat_b + i; }
    else if (i < n2) { s = Wx + (i - n1);   d = Wx_b + (i - n1); }
    else             { s = Wh + (i - n2);   d = Wh_b + (i - n2); }
    float4 a = *(const float4*)s;
    float4 b = *(const float4*)(s + 4);
    unsigned short r[8] = {f2bf(a.x), f2bf(a.y), f2bf(a.z), f2bf(a.w),
                           f2bf(b.x), f2bf(b.y), f2bf(b.z), f2bf(b.w)};
    *(s16x8*)d = *(const s16x8*)r;
}

__global__ __launch_bounds__(256) void init_kernel(
    const float* __restrict__ root_h, const float* __restrict__ root_c,
    unsigned short* __restrict__ h_buf, float* __restrict__ c_buf)
{
    const int i = blockIdx.x * 256 + threadIdx.x;
    if (i < HD) { h_buf[i] = f2bf(root_h[i]); c_buf[i] = root_c[i]; }
}

// ---------------------------------------------------------------------------
// xproj = feat @ Wx^T + (bx+bh). 256x256 BK=64 kk-split (R7-proven).
// ---------------------------------------------------------------------------
__global__ __launch_bounds__(512, 2) void xproj_8ph(
    const unsigned short* __restrict__ Ab,
    const unsigned short* __restrict__ Bb,
    const float* __restrict__ bx, const float* __restrict__ bh,
    float* __restrict__ xproj)
{
    __shared__ char lds[131072];
    const int tid = threadIdx.x;
    const int wid = tid >> 6;
    const int lane = tid & 63;
    const int wr = wid >> 2;
    const int wc = wid & 3;
    const int bm = blockIdx.x * 256;
    const int bn = blockIdx.y * 256;
    const int fr = lane & 15;
    const int fq = lane >> 4;

    const int srow = tid >> 3;
    const int sslot = (tid & 7) ^ (srow & 7);
    const unsigned short* gA[4];
    const unsigned short* gB[4];
    #pragma unroll
    for (int q = 0; q < 4; ++q) {
        gA[q] = Ab + (size_t)(bm + q * 64 + srow) * FEAT + sslot * 8;
        gB[q] = Bb + (size_t)(bn + q * 64 + srow) * FEAT + sslot * 8;
    }
    const int ldsoff = tid * 16;

    f32x4 acc[8][4];
    #pragma unroll
    for (int i = 0; i < 8; ++i)
        #pragma unroll
        for (int j = 0; j < 4; ++j) { f32x4 z = {0.f, 0.f, 0.f, 0.f}; acc[i][j] = z; }

    #pragma unroll
    for (int q = 0; q < 4; ++q) {
        gload_lds16(gA[q], lds + q * 8192 + ldsoff);
        gload_lds16(gB[q], lds + 32768 + q * 8192 + ldsoff);
    }

    for (int t = 0; t < 32; ++t) {
        const int d = t & 1;
        const char* LA = lds + d * 65536;
        const char* LB = LA + 32768;
        char* SA = lds + (d ^ 1) * 65536;
        char* SB = SA + 32768;
        const int knext = (t + 1) * 64;

        asm volatile("s_waitcnt vmcnt(0)" ::: "memory");
        __builtin_amdgcn_s_barrier();

        #pragma unroll
        for (int kk = 0; kk < 2; ++kk) {
            const int kbyte = kk * 64 + fq * 16;
            s16x8 aF[8], bF[4];
            #pragma unroll
            for (int i = 0; i < 8; ++i) {
                const int row = wr * 128 + i * 16 + fr;
                aF[i] = *(const s16x8*)(LA + row * 128 + (kbyte ^ ((row & 7) << 4)));
            }
            #pragma unroll
            for (int j = 0; j < 4; ++j) {
                const int row = wc * 64 + j * 16 + fr;
                bF[j] = *(const s16x8*)(LB + row * 128 + (kbyte ^ ((row & 7) << 4)));
            }
            if (t < 31) {
                if (kk == 0) {
                    #pragma unroll
                    for (int q = 0; q < 4; ++q)
                        gload_lds16(gA[q] + knext, SA + q * 8192 + ldsoff);
                } else {
                    #pragma unroll
                    for (int q = 0; q < 4; ++q)
                        gload_lds16(gB[q] + knext, SB + q * 8192 + ldsoff);
                }
            }
            __builtin_amdgcn_s_setprio(1);
            #pragma unroll
            for (int i = 0; i < 8; ++i)
                #pragma unroll
                for (int j = 0; j < 4; ++j)
                    acc[i][j] = __builtin_amdgcn_mfma_f32_16x16x32_bf16(
                        aF[i], bF[j], acc[i][j], 0, 0, 0);
            __builtin_amdgcn_s_setprio(0);
        }
    }

    #pragma unroll
    for (int j = 0; j < 4; ++j) {
        const int col = bn + wc * 64 + j * 16 + fr;
        const float bias = bx[col] + bh[col];
        #pragma unroll
        for (int i = 0; i < 8; ++i) {
            const int rowb = bm + wr * 128 + i * 16 + fq * 4;
            #pragma unroll
            for (int reg = 0; reg < 4; ++reg)
                xproj[(size_t)(rowb + reg) * FH + col] = acc[i][j][reg] + bias;
        }
    }
}

// ---------------------------------------------------------------------------
// Large levels, gather-free WITHOUT extra buffers: parents of level nodes are
// the contiguous range [prevstart, start); node t = start + r has parent
// prevstart + (r>>1). A-tile stages h_buf rows prevstart+(r>>1)+1 directly
// (per-lane global source of global_load_lds). B mapping: tile row r ->
// Wh row ((r>>4)&3)*1024 + jg0 + (r>>6)*16 + (r&15), so wave wc's fragment
// j = gate j at within-gate cols jg0+wc*16+[0,16) -> gates in-register.
// BM in {64,128,256}: every level is exactly (16,16) = 256 blocks.
// ---------------------------------------------------------------------------
template<int BM>
__global__ __launch_bounds__(512, 2) void level_kk(
    const float* __restrict__ xproj, const unsigned short* __restrict__ Whb,
    int start, int prevstart, unsigned short* __restrict__ h_buf,
    float* __restrict__ c_buf, float* __restrict__ out)
{
    constexpr int MR = BM / 32;              // A frags per wave
    constexpr int ABYTES = BM * 128;         // A-tile bytes per buffer
    constexpr int BUF = ABYTES + 32768;      // + B-tile (256 rows x 128 B)
    __shared__ char lds[2 * BUF];
    const int tid = threadIdx.x;
    const int wid = tid >> 6, lane = tid & 63;
    const int wr = wid >> 2, wc = wid & 3;
    const int fr = lane & 15, fq = lane >> 4;
    const int t0 = start + blockIdx.x * BM;
    const int jg0 = blockIdx.y * 64;

    const int srow = tid >> 3;
    const int sslot = (tid & 7) ^ (srow & 7);
    const unsigned short* gA[BM / 64];
    #pragma unroll
    for (int q = 0; q < BM / 64; ++q) {
        const int rg = blockIdx.x * BM + q * 64 + srow;       // node offset in level
        gA[q] = h_buf + (size_t)(prevstart + (rg >> 1) + 1) * HD + sslot * 8;
    }
    const unsigned short* gB[4];
    #pragma unroll
    for (int q = 0; q < 4; ++q) {
        const int r = q * 64 + srow;
        const int whrow = ((r >> 4) & 3) * 1024 + jg0 + ((r >> 6) * 16) + (r & 15);
        gB[q] = Whb + (size_t)whrow * HD + sslot * 8;
    }
    const int ldsoff = tid * 16;

    f32x4 acc[MR][4];
    #pragma unroll
    for (int i = 0; i < MR; ++i)
        #pragma unroll
        for (int j = 0; j < 4; ++j) { f32x4 z = {0.f, 0.f, 0.f, 0.f}; acc[i][j] = z; }

    #pragma unroll
    for (int q = 0; q < BM / 64; ++q)
        gload_lds16(gA[q], lds + q * 8192 + ldsoff);
    #pragma unroll
    for (int q = 0; q < 4; ++q)
        gload_lds16(gB[q], lds + ABYTES + q * 8192 + ldsoff);

    for (int t = 0; t < 16; ++t) {
        const char* LA = lds + (t & 1) * BUF;
        const char* LB = LA + ABYTES;
        char* SA = lds + ((t & 1) ^ 1) * BUF;
        char* SB = SA + ABYTES;
        const int knext = (t + 1) * 64;

        asm volatile("s_waitcnt vmcnt(0)" ::: "memory");
        __builtin_amdgcn_s_barrier();

        #pragma unroll
        for (int kk = 0; kk < 2; ++kk) {
            const int kbyte = kk * 64 + fq * 16;
            s16x8 aF[MR], bF[4];
            #pragma unroll
            for (int i = 0; i < MR; ++i) {
                const int row = wr * (BM / 2) + i * 16 + fr;
                aF[i] = *(const s16x8*)(LA + row * 128 + (kbyte ^ ((row & 7) << 4)));
            }
            #pragma unroll
            for (int j = 0; j < 4; ++j) {
                const int row = wc * 64 + j * 16 + fr;
                bF[j] = *(const s16x8*)(LB + row * 128 + (kbyte ^ ((row & 7) << 4)));
            }
            if (t < 15) {
                if (kk == 0) {
                    #pragma unroll
                    for (int q = 0; q < BM / 64; ++q)
                        gload_lds16(gA[q] + knext, SA + q * 8192 + ldsoff);
                } else {
                    #pragma unroll
                    for (int q = 0; q < 4; ++q)
                        gload_lds16(gB[q] + knext, SB + q * 8192 + ldsoff);
                }
            }
            __builtin_amdgcn_s_setprio(1);
            #pragma unroll
            for (int i = 0; i < MR; ++i)
                #pragma unroll
                for (int j = 0; j < 4; ++j)
                    acc[i][j] = __builtin_amdgcn_mfma_f32_16x16x32_bf16(
                        aF[i], bF[j], acc[i][j], 0, 0, 0);
            __builtin_amdgcn_s_setprio(0);
        }
    }

    // epilogue: acc[i][g] = gate g at col jg0+wc*16+fr for node rows
    const int col = jg0 + wc * 16 + fr;
    #pragma unroll
    for (int i = 0; i < MR; ++i) {
        #pragma unroll
        for (int reg = 0; reg < 4; ++reg) {
            const int t = t0 + wr * (BM / 2) + i * 16 + fq * 4 + reg;
            const int p = (t - 1) >> 1;
            const size_t xb = (size_t)t * FH + col;
            const float gi = acc[i][0][reg] + xproj[xb];
            const float go = acc[i][1][reg] + xproj[xb + HD];
            const float gf = acc[i][2][reg] + xproj[xb + 2 * HD];
            const float gu = acc[i][3][reg] + xproj[xb + 3 * HD];
            const float cp = c_buf[(size_t)(p + 1) * HD + col];
            const float c = fast_sig(gi) * fast_tanh(gu) + fast_sig(gf) * cp;
            const float h = fast_sig(go) * fast_tanh(c);
            c_buf[(size_t)(t + 1) * HD + col] = c;
            h_buf[(size_t)(t + 1) * HD + col] = f2bf(h);
            out[(size_t)t * HD + col] = h;
        }
    }
}

// ---------------------------------------------------------------------------
// Shared gate epilogue (small levels, parent[] gather path)
// ---------------------------------------------------------------------------
__device__ __forceinline__ void level_epilogue(
    f32x4 (&acc)[4][4], const float* __restrict__ xproj,
    const int* __restrict__ parent, unsigned short* __restrict__ h_buf,
    float* __restrict__ c_buf, float* __restrict__ out,
    int t0, int lim, int wm, int col, int fq)
{
    #pragma unroll
    for (int i = 0; i < 4; ++i) {
        #pragma unroll
        for (int reg = 0; reg < 4; ++reg) {
            const int t = t0 + wm + i * 16 + fq * 4 + reg;
            if (t < lim) {
                const int p = parent[t];
                const size_t xb = (size_t)t * FH + col;
                const float gi = acc[i][0][reg] + xproj[xb];
                const float go = acc[i][1][reg] + xproj[xb + HD];
                const float gf = acc[i][2][reg] + xproj[xb + 2 * HD];
                const float gu = acc[i][3][reg] + xproj[xb + 3 * HD];
                const float cp = c_buf[(size_t)(p + 1) * HD + col];
                const float c = fast_sig(gi) * fast_tanh(gu) + fast_sig(gf) * cp;
                const float h = fast_sig(go) * fast_tanh(c);
                c_buf[(size_t)(t + 1) * HD + col] = c;
                h_buf[(size_t)(t + 1) * HD + col] = f2bf(h);
                out[(size_t)t * HD + col] = h;
            }
        }
    }
}

// ---------------------------------------------------------------------------
// BK=128 helpers (small levels)
// ---------------------------------------------------------------------------
__device__ __forceinline__ void bk128_issue(
    const unsigned short* const (&gA)[8], const unsigned short* const (&gB)[8],
    int k0, unsigned short* As, unsigned short* Bs, int wbase)
{
    #pragma unroll
    for (int q = 0; q < 8; ++q) {
        gload_lds16(gA[q] + k0, (char*)As + q * 4096 + wbase);
        gload_lds16(gB[q] + k0, (char*)Bs + q * 4096 + wbase);
    }
}

__device__ __forceinline__ void bk128_compute(
    const unsigned short* As, const unsigned short* Bs,
    f32x4 (&acc)[4][4], int wm, int wn16, int fr, int fkb)
{
    #pragma unroll
    for (int kk = 0; kk < 4; ++kk) {
        s16x8 aF[4], bF[4];
        #pragma unroll
        for (int i = 0; i < 4; ++i) {
            const int r = wm + i * 16 + fr;
            const int byteIn = (kk * 64 + fkb) ^ ((r & 7) << 4);
            aF[i] = *(const s16x8*)((const char*)As + r * 256 + byteIn);
        }
        #pragma unroll
        for (int g = 0; g < 4; ++g) {
            const int r = g * 32 + wn16 + fr;
            const int byteIn = (kk * 64 + fkb) ^ ((r & 7) << 4);
            bF[g] = *(const s16x8*)((const char*)Bs + r * 256 + byteIn);
        }
        #pragma unroll
        for (int i = 0; i < 4; ++i)
            #pragma unroll
            for (int g = 0; g < 4; ++g)
                acc[i][g] = __builtin_amdgcn_mfma_f32_16x16x32_bf16(aF[i], bF[g], acc[i][g], 0, 0, 0);
    }
}

// ---------------------------------------------------------------------------
// Small levels (count <= 512): BK=128 double-buffered (R5-proven)
// ---------------------------------------------------------------------------
__global__ __launch_bounds__(256) void level_bk128_dbuf(
    const float* __restrict__ xproj, const unsigned short* __restrict__ Whb,
    const int* __restrict__ parent, unsigned short* __restrict__ h_buf,
    float* __restrict__ c_buf, float* __restrict__ out,
    int start, int count)
{
    __shared__ unsigned short As0[128 * 128];
    __shared__ unsigned short Bs0[128 * 128];
    __shared__ unsigned short As1[128 * 128];
    __shared__ unsigned short Bs1[128 * 128];
    const int tid = threadIdx.x;
    const int wid = tid >> 6;
    const int lane = tid & 63;
    const int t0 = start + blockIdx.x * 128;
    const int jg0 = blockIdx.y * 32;
    const int lim = start + count;
    const int wm = (wid & 1) * 64;
    const int wn16 = (wid >> 1) * 16;
    const int wbase = wid * 1024;
    const int srow_b = tid >> 4;
    const int rowbyte = (tid & 15) * 16;

    const unsigned short* gA[8];
    const unsigned short* gB[8];
    #pragma unroll
    for (int q = 0; q < 8; ++q) {
        const int r = q * 16 + srow_b;
        const int sk = (rowbyte ^ ((r & 7) << 4)) >> 1;
        const int tA = min(t0 + r, lim - 1);
        gA[q] = h_buf + (size_t)(parent[tA] + 1) * HD + sk;
        const int whrow = ((r >> 5) << 10) + jg0 + (r & 31);
        gB[q] = Whb + (size_t)whrow * HD + sk;
    }

    f32x4 acc[4][4];
    #pragma unroll
    for (int i = 0; i < 4; ++i)
        #pragma unroll
        for (int g = 0; g < 4; ++g) { f32x4 z = {0.f, 0.f, 0.f, 0.f}; acc[i][g] = z; }

    const int fr = lane & 15;
    const int fkb = (lane >> 4) * 16;

    bk128_issue(gA, gB, 0, As0, Bs0, wbase);
    #pragma unroll
    for (int t = 0; t < 8; ++t) {
        unsigned short* curA = (t & 1) ? As1 : As0;
        unsigned short* curB = (t & 1) ? Bs1 : Bs0;
        unsigned short* nxtA = (t & 1) ? As0 : As1;
        unsigned short* nxtB = (t & 1) ? Bs0 : Bs1;
        if (t < 7) {
            bk128_issue(gA, gB, (t + 1) * 128, nxtA, nxtB, wbase);
            asm volatile("s_waitcnt vmcnt(16)" ::: "memory");
        } else {
            asm volatile("s_waitcnt vmcnt(0)" ::: "memory");
        }
        __builtin_amdgcn_s_barrier();
        __builtin_amdgcn_sched_barrier(0);
        bk128_compute(curA, curB, acc, wm, wn16, fr, fkb);
        __builtin_amdgcn_sched_barrier(0);
        __builtin_amdgcn_s_barrier();
    }

    level_epilogue(acc, xproj, parent, h_buf, c_buf, out,
                   t0, lim, wm, jg0 + wn16 + fr, lane >> 4);
}

extern "C" void kernel_launch(void* const* d_in, const int* in_sizes, int n_in,
                              void* d_out, int out_size, void* d_ws, size_t ws_size,
                              hipStream_t stream) {
    const float* feat   = (const float*)d_in[0];
    const float* Wx     = (const float*)d_in[1];
    const float* bx     = (const float*)d_in[2];
    const float* Wh     = (const float*)d_in[3];
    const float* bh     = (const float*)d_in[4];
    const int*   parent = (const int*)d_in[5];
    const float* root_c = (const float*)d_in[6];
    const float* root_h = (const float*)d_in[7];
    float* out = (float*)d_out;

    char* ws = (char*)d_ws;
    float* xproj = (float*)ws;                          ws += (size_t)NN * FH * 4;
    float* c_buf = (float*)ws;                          ws += (size_t)(NN + 1) * HD * 4;
    unsigned short* feat_b = (unsigned short*)ws;       ws += (size_t)NN * FEAT * 2;
    unsigned short* Wx_b = (unsigned short*)ws;         ws += (size_t)FH * FEAT * 2;
    unsigned short* Wh_b = (unsigned short*)ws;         ws += (size_t)FH * HD * 2;
    unsigned short* h_buf = (unsigned short*)ws;        ws += (size_t)(NN + 1) * HD * 2;

    const size_t ntot = (size_t)NN * FEAT + (size_t)FH * FEAT + (size_t)FH * HD;
    convert_all_kernel<<<(unsigned)(ntot / 8 / 256), 256, 0, stream>>>(
        feat, Wx, Wh, feat_b, Wx_b, Wh_b);
    init_kernel<<<4, 256, 0, stream>>>(root_h, root_c, h_buf, c_buf);

    dim3 g1(NN / 256, FH / 256);
    xproj_8ph<<<g1, 512, 0, stream>>>(feat_b, Wx_b, bx, bh, xproj);

    // small levels (counts 1..512), gathered via parent[]
    for (int start = 0, sz = 1; sz <= 512; start += sz, sz *= 2) {
        dim3 g2((sz + 127) / 128, HD / 32);
        level_bk128_dbuf<<<g2, 256, 0, stream>>>(
            xproj, Wh_b, parent, h_buf, c_buf, out, start, sz);
    }

    // large levels: gather-free kk-split, each exactly 256 blocks
    dim3 gl(16, 16);
    level_kk<64><<<gl, 512, 0, stream>>>(xproj, Wh_b, 1023, 511,
                                         h_buf, c_buf, out);
    level_kk<128><<<gl, 512, 0, stream>>>(xproj, Wh_b, 2047, 1023,
                                          h_buf, c_buf, out);
    level_kk<256><<<gl, 512, 0, stream>>>(xproj, Wh_b, 4095, 2047,
                                          h_buf, c_buf, out);

    // straggler node 8191 (parent 4095 via h_buf/c_buf)
    dim3 g3(1, HD / 32);
    level_bk128_dbuf<<<g3, 256, 0, stream>>>(
        xproj, Wh_b, parent, h_buf, c_buf, out, 8191, 1);
}